// Round 1
// baseline (381.195 us; speedup 1.0000x reference)
//
#include <hip/hip_runtime.h>
#include <stdint.h>

// B=4, T=1024, D=1024, H=16, DH=64. fp32 in/out, absmax thr 0.1.
// R9 vs R8 (flash_attn only; everything else unchanged):
//  - latency-bound fix: 512-thread blocks = 4 q-waves x 2 kb-half waves.
//    Partial lsum/acc are linearly additive (fixed-shift exp2 softmax, no
//    running max) -> combine via LDS at the end. 4096 waves total ->
//    4 waves/SIMD (was 2); max per-wave kb trips 8 -> 4.
//    __launch_bounds__(512,4) caps VGPR at 128 (current use 116, no spill).
//  - XCD-aware bid mapping: all 8 q-blocks of a head share an XCD (L2 K/V
//    reuse); qb interleaved 0,7,1,6,... so adjacent blocks pair long+short.

#define B_  4
#define T_  1024
#define D_  1024
#define H_  16
#define DH_ 64

typedef __attribute__((ext_vector_type(8))) short short8;
typedef __attribute__((ext_vector_type(4))) float floatx4;
typedef __attribute__((ext_vector_type(4))) _Float16 half4;

__device__ __forceinline__ unsigned short f2bf(float f) {
  union { float f; uint32_t u; } a; a.f = f;
  uint32_t r = a.u + 0x7FFFu + ((a.u >> 16) & 1u);
  return (unsigned short)(r >> 16);
}
__device__ __forceinline__ float bf2f(unsigned short u) {
  union { uint32_t u; float f; } a; a.u = ((uint32_t)u) << 16;
  return a.f;
}

#define GLD_LDS16(g, l) __builtin_amdgcn_global_load_lds( \
    (const __attribute__((address_space(1))) unsigned int*)(g), \
    (__attribute__((address_space(3))) unsigned int*)(l), 16, 0, 0)

// ---------------------------------------------- prep: cast x + transpose W
__global__ __launch_bounds__(256)
void prep_kernel(const float4* __restrict__ x4, unsigned short* __restrict__ xb,
                 const float* __restrict__ w0, const float* __restrict__ w1,
                 const float* __restrict__ w2, const float* __restrict__ w3,
                 const float* __restrict__ w4, unsigned short* __restrict__ dst_all) {
  const int t = threadIdx.x;
  if (blockIdx.x < 4096) {
    int idx = blockIdx.x * 256 + t;
    float4 v = x4[idx];
    union { uint2 u; unsigned short s[4]; } o;
    o.s[0] = f2bf(v.x); o.s[1] = f2bf(v.y); o.s[2] = f2bf(v.z); o.s[3] = f2bf(v.w);
    *(uint2*)&xb[(size_t)idx * 4] = o.u;
    return;
  }
  const int b = blockIdx.x - 4096;
  const int z = b >> 8, ky = (b >> 4) & 15, nx = b & 15;
  const float* src = (z == 0) ? w0 : (z == 1) ? w1 : (z == 2) ? w2 : (z == 3) ? w3 : w4;
  unsigned short* dst = dst_all + (size_t)z * D_ * D_;
  __shared__ __align__(16) unsigned short tile[64 * 72];
  const int k0 = ky * 64, n0 = nx * 64;
#pragma unroll
  for (int c = 0; c < 4; ++c) {
    int idx = c * 256 + t;
    int r = idx >> 4, cc = (idx & 15) << 2;
    float4 v = *(const float4*)&src[(size_t)(k0 + r) * D_ + n0 + cc];
    tile[(cc + 0) * 72 + r] = f2bf(v.x);
    tile[(cc + 1) * 72 + r] = f2bf(v.y);
    tile[(cc + 2) * 72 + r] = f2bf(v.z);
    tile[(cc + 3) * 72 + r] = f2bf(v.w);
  }
  __syncthreads();
  int rr = t >> 2, ck = (t & 3) << 4;
  uint4 v0 = *(const uint4*)&tile[rr * 72 + ck];
  uint4 v1 = *(const uint4*)&tile[rr * 72 + ck + 8];
  *(uint4*)&dst[(size_t)(n0 + rr) * D_ + k0 + ck] = v0;
  *(uint4*)&dst[(size_t)(n0 + rr) * D_ + k0 + ck + 8] = v1;
}

// ------------------------------------------------------------------ QKV GEMM
// Q pre-scaled by 0.125*log2(e); Q,K bf16 -> [B,H,T,DH]; V fp16 k-shuffled
// V^T [d][kb][quad][j][r] staged via LDS for coalesced stores.
__global__ __launch_bounds__(256, 2)
void gemm_qkv(const unsigned short* __restrict__ A,
              const unsigned short* __restrict__ Bt,
              unsigned short* __restrict__ oQ, unsigned short* __restrict__ oK,
              _Float16* __restrict__ oV) {
  const int K = 1024;
  __shared__ __align__(16) unsigned short As[128 * 32];
  __shared__ __align__(16) unsigned short Bs[128 * 32];
  __shared__ __align__(16) _Float16 Cs[2 * 64 * 136];
  const int t = threadIdx.x;
  const int lane = t & 63, w = t >> 6;
  const int quad = lane >> 4, lm = lane & 15;
  const int wm = w >> 1, wn = w & 1;
  const int m0 = blockIdx.y * 128, n0 = blockIdx.x * 128;
  const int arow = w * 32 + (lane >> 2), acol = (lane & 3) << 3;

  floatx4 acc[4][4];
#pragma unroll
  for (int i = 0; i < 4; ++i)
#pragma unroll
    for (int j = 0; j < 4; ++j) acc[i][j] = (floatx4){0.f, 0.f, 0.f, 0.f};

  for (int kt = 0; kt < K; kt += 32) {
    const unsigned short* ga = A + (size_t)(m0 + arow) * K + kt + acol;
    const unsigned short* gb = Bt + (size_t)(n0 + arow) * K + kt + acol;
    GLD_LDS16(ga, &As[(w * 32) * 32]);
    GLD_LDS16(ga + (size_t)16 * K, &As[(w * 32 + 16) * 32]);
    GLD_LDS16(gb, &Bs[(w * 32) * 32]);
    GLD_LDS16(gb + (size_t)16 * K, &Bs[(w * 32 + 16) * 32]);
    __syncthreads();
    short8 a[4], b[4];
#pragma unroll
    for (int i = 0; i < 4; ++i) a[i] = *(const short8*)&As[(wm * 64 + i * 16 + lm) * 32 + quad * 8];
#pragma unroll
    for (int j = 0; j < 4; ++j) b[j] = *(const short8*)&Bs[(wn * 64 + j * 16 + lm) * 32 + quad * 8];
#pragma unroll
    for (int i = 0; i < 4; ++i)
#pragma unroll
      for (int j = 0; j < 4; ++j)
        acc[i][j] = __builtin_amdgcn_mfma_f32_16x16x32_bf16(a[i], b[j], acc[i][j], 0, 0, 0);
    __syncthreads();
  }

  if (n0 < 2048) {
    unsigned short* p = (n0 < 1024) ? oQ : oK;
    const float qscale = (n0 < 1024) ? 0.18033688f : 1.0f;   // 0.125*log2(e)
#pragma unroll
    for (int i = 0; i < 4; ++i) {
      int gmb = m0 + wm * 64 + i * 16 + quad * 4;
#pragma unroll
      for (int j = 0; j < 4; ++j) {
        int gn = n0 + wn * 64 + j * 16 + lm;
        int nn = gn & 1023, hh = nn >> 6, dd = nn & 63;
#pragma unroll
        for (int r = 0; r < 4; ++r) {
          int gm = gmb + r;
          int bb = gm >> 10, tt = gm & 1023;
          p[(((size_t)bb * H_ + hh) * T_ + tt) * DH_ + dd] = f2bf(acc[i][j][r] * qscale);
        }
      }
    }
  } else {
#pragma unroll
    for (int i = 0; i < 4; ++i) {
#pragma unroll
      for (int j = 0; j < 4; ++j) {
        int gn = n0 + wn * 64 + j * 16 + lm;
        int hd = (gn >> 6) & 1, dd = gn & 63;
        int kperm = quad * 32 + (wm * 4 + i) * 4;
        union { _Float16 h[4]; uint2 u; } pk;
#pragma unroll
        for (int r = 0; r < 4; ++r) pk.h[r] = (_Float16)acc[i][j][r];
        *(uint2*)&Cs[((size_t)(hd * 64 + dd)) * 136 + kperm] = pk.u;
      }
    }
    __syncthreads();
    const int row = t >> 1, half = t & 1;
    const int hd = row >> 6, dd = row & 63;
    const int hh = ((n0 & 1023) >> 6) + hd;
    const int bb = m0 >> 10, kbg = (m0 >> 7) & 7;
    const _Float16* srcp = &Cs[(size_t)(hd * 64 + dd) * 136 + half * 64];
    _Float16* dstp = oV + ((((size_t)bb * H_ + hh) * DH_ + dd) * 8 + kbg) * 128 + half * 64;
#pragma unroll
    for (int g = 0; g < 8; ++g)
      *(uint4*)(dstp + g * 8) = *(const uint4*)(srcp + g * 8);
  }
}

// ------------------------------------------------------------ FFN GEMM 64x128
template <int MODE>
__global__ __launch_bounds__(256, 2)
void gemm_ffn(const unsigned short* __restrict__ A,
              const unsigned short* __restrict__ Bt,
              unsigned short* __restrict__ oBf, float* __restrict__ oF,
              const float* __restrict__ bias) {
  const int K = 1024, N = 1024;
  __shared__ __align__(16) unsigned short As[64 * 32];
  __shared__ __align__(16) unsigned short Bs[128 * 32];
  const int t = threadIdx.x;
  const int lane = t & 63, w = t >> 6;
  const int quad = lane >> 4, lm = lane & 15;
  const int wm = w >> 1, wn = w & 1;
  const int m0 = blockIdx.y * 64, n0 = blockIdx.x * 128;
  const int lrow = lane >> 2, lcol = (lane & 3) << 3;

  floatx4 acc[2][4];
#pragma unroll
  for (int i = 0; i < 2; ++i)
#pragma unroll
    for (int j = 0; j < 4; ++j) acc[i][j] = (floatx4){0.f, 0.f, 0.f, 0.f};

  for (int kt = 0; kt < K; kt += 32) {
    const unsigned short* ga = A + (size_t)(m0 + w * 16 + lrow) * K + kt + lcol;
    const unsigned short* gb = Bt + (size_t)(n0 + w * 32 + lrow) * K + kt + lcol;
    GLD_LDS16(ga, &As[(w * 16) * 32]);
    GLD_LDS16(gb, &Bs[(w * 32) * 32]);
    GLD_LDS16(gb + (size_t)16 * K, &Bs[(w * 32 + 16) * 32]);
    __syncthreads();
    short8 a[2], b[4];
#pragma unroll
    for (int i = 0; i < 2; ++i) a[i] = *(const short8*)&As[(wm * 32 + i * 16 + lm) * 32 + quad * 8];
#pragma unroll
    for (int j = 0; j < 4; ++j) b[j] = *(const short8*)&Bs[(wn * 64 + j * 16 + lm) * 32 + quad * 8];
#pragma unroll
    for (int i = 0; i < 2; ++i)
#pragma unroll
      for (int j = 0; j < 4; ++j)
        acc[i][j] = __builtin_amdgcn_mfma_f32_16x16x32_bf16(a[i], b[j], acc[i][j], 0, 0, 0);
    __syncthreads();
  }

#pragma unroll
  for (int i = 0; i < 2; ++i) {
    int gmb = m0 + wm * 32 + i * 16 + quad * 4;
#pragma unroll
    for (int j = 0; j < 4; ++j) {
      int gn = n0 + wn * 64 + j * 16 + lm;
      float bv = bias[gn];
#pragma unroll
      for (int r = 0; r < 4; ++r) {
        int gm = gmb + r;
        float v = acc[i][j][r] + bv;
        if (MODE == 1) {
          oBf[(size_t)gm * N + gn] = f2bf(fmaxf(v, 0.f));
        } else {
          oF[(size_t)gm * N + gn] = v;
        }
      }
    }
  }
}

// --------------------------------------------------------------- flash attn
// 512 blocks x 512 thr = 8 waves: 4 q-row waves (qw) x 2 kb-halves (kh).
// Fixed-shift exp2 softmax (no running max) -> partial lsum/acc add linearly;
// kh=1 waves dump partials to LDS, kh=0 waves combine + epilogue.
// Rotating per-j K-prefetch kept from R8 (latency hidden, no spill array).
// XCD mapping: bid&7 = head%8 (all 8 q-blocks of a head on one XCD for L2
// K/V reuse); qslot interleaved 0,7,1,6,2,5,3,4 so adjacent blocks pair
// long+short kb ranges.
__global__ __launch_bounds__(512, 4)
void flash_attn(const unsigned short* __restrict__ Qb,
                const unsigned short* __restrict__ Kb,
                const _Float16* __restrict__ Vtg,
                const float* __restrict__ maskp,
                unsigned short* __restrict__ attn) {
  const int t = threadIdx.x;
  const int lane = t & 63, w = t >> 6;
  const int quad = lane >> 4, lm = lane & 15;
  const int qw = w & 3, kh = w >> 2;

  const int bid = blockIdx.x;
  const int xcd = bid & 7;
  const int qslot = (bid >> 3) & 7;
  const int hgrp = bid >> 6;
  const int head = hgrp * 8 + xcd;          // 0..63
  const int qh = qslot >> 1;
  const int qb = (qslot & 1) ? 7 - qh : qh; // 0,7,1,6,2,5,3,4
  const int hh = head & 15, bb = head >> 4;
  const int q0 = qb << 7;

  const size_t headoff = ((size_t)bb * H_ + hh) * T_ * DH_;
  const unsigned short* Qh = Qb + headoff;
  const unsigned short* Kh = Kb + headoff;
  const _Float16* Vh = Vtg + headoff;   // k-shuffled [d][kb][quad][j][r]

  short8 qf[2][2];
#pragma unroll
  for (int qg = 0; qg < 2; ++qg)
#pragma unroll
    for (int ks = 0; ks < 2; ++ks)
      qf[qg][ks] = *(const short8*)(Qh + (size_t)(q0 + qw * 32 + qg * 16 + lm) * 64 + ks * 32 + quad * 8);

  float lsum[2] = {0.f, 0.f};
  floatx4 acc[2][4];
#pragma unroll
  for (int qg = 0; qg < 2; ++qg)
#pragma unroll
    for (int j2 = 0; j2 < 4; ++j2) acc[qg][j2] = (floatx4){0.f, 0.f, 0.f, 0.f};

  const int qglob0 = q0 + qw * 32 + lm;
  const bool excl1 = (qglob0 + 16 == 1023);   // row-1023 lane (qg=1 only)
  const float MSHIFT = 14426.950408f;          // 10000*log2(e)

  const int kb_lo = (qb == 7 && qw == 3) ? 0 : qb;
  const int cnt = 8 - kb_lo;
  const int halfc = (cnt + 1) >> 1;
  const int kb_begin = kh ? kb_lo + halfc : kb_lo;
  const int kb_end   = kh ? 8 : kb_lo + halfc;

  // prologue: K fragments for kb_begin
  short8 kf[8][2];
  if (kb_begin < kb_end) {
    const unsigned short* Kblk = Kh + (size_t)(kb_begin * 128) * 64;
#pragma unroll
    for (int j = 0; j < 8; ++j) {
      kf[j][0] = *(const short8*)(Kblk + (size_t)(j * 16 + lm) * 64 + quad * 8);
      kf[j][1] = *(const short8*)(Kblk + (size_t)(j * 16 + lm) * 64 + 32 + quad * 8);
    }
  }

  for (int kb = kb_begin; kb < kb_end; ++kb) {
    const int k0 = kb * 128;
    const bool need_mask = (kb <= qb);
    const bool has_next = (kb + 1 < kb_end);
    const unsigned short* Kn = Kh + (size_t)((kb + 1) * 128) * 64;

    // V loads for this kb (consumed in PV; hidden by S+softmax of j=0..)
    union { uint4 u[4]; _Float16 h[32]; } vf[4];
#pragma unroll
    for (int j2 = 0; j2 < 4; ++j2) {
      const _Float16* vp = Vh + ((size_t)(j2 * 16 + lm) * 8 + kb) * 128 + quad * 32;
#pragma unroll
      for (int g = 0; g < 4; ++g) vf[j2].u[g] = *(const uint4*)(vp + g * 8);
    }

#pragma unroll
    for (int j = 0; j < 8; ++j) {
      // S-MFMAs consume kf[j]
      floatx4 st[2];
#pragma unroll
      for (int qg = 0; qg < 2; ++qg) {
        floatx4 z = (floatx4){0.f, 0.f, 0.f, 0.f};
        z = __builtin_amdgcn_mfma_f32_16x16x32_bf16(kf[j][0], qf[qg][0], z, 0, 0, 0);
        st[qg] = __builtin_amdgcn_mfma_f32_16x16x32_bf16(kf[j][1], qf[qg][1], z, 0, 0, 0);
      }
      // rotate: prefetch kb+1's fragment j into kf[j] (lands ~7 j-steps later)
      if (has_next) {
        kf[j][0] = *(const short8*)(Kn + (size_t)(j * 16 + lm) * 64 + quad * 8);
        kf[j][1] = *(const short8*)(Kn + (size_t)(j * 16 + lm) * 64 + 32 + quad * 8);
      }
      // softmax j
      half4 pa[2];
#pragma unroll
      for (int qg = 0; qg < 2; ++qg) {
        const int qq = qglob0 + qg * 16;
        const bool skip = (qg == 1) && excl1;
#pragma unroll
        for (int r = 0; r < 4; ++r) {
          int kg = k0 + j * 16 + quad * 4 + r;
          float v = st[qg][r];
          if (need_mask && !skip && kg <= qq) v -= MSHIFT;
          float p = __builtin_amdgcn_exp2f(v);
          lsum[qg] += p;
          pa[qg][r] = (_Float16)p;
        }
      }
      // PV j
#pragma unroll
      for (int j2 = 0; j2 < 4; ++j2) {
        half4 vb;
#pragma unroll
        for (int r = 0; r < 4; ++r) vb[r] = vf[j2].h[j * 4 + r];
        acc[0][j2] = __builtin_amdgcn_mfma_f32_16x16x16f16(pa[0], vb, acc[0][j2], 0, 0, 0);
        acc[1][j2] = __builtin_amdgcn_mfma_f32_16x16x16f16(pa[1], vb, acc[1][j2], 0, 0, 0);
      }
    }
  }

  // combine kh=1 partials into kh=0 waves via LDS, then epilogue (kh=0 only).
  // layout [qw][elem][lane]: lane-contiguous -> conflict-free.
  __shared__ float comb[4][34][64];
  if (kh == 1) {
    float* p = &comb[qw][0][lane];
#pragma unroll
    for (int qg = 0; qg < 2; ++qg)
#pragma unroll
      for (int j2 = 0; j2 < 4; ++j2)
#pragma unroll
        for (int r = 0; r < 4; ++r)
          p[((qg * 4 + j2) * 4 + r) * 64] = acc[qg][j2][r];
    p[32 * 64] = lsum[0];
    p[33 * 64] = lsum[1];
  }
  __syncthreads();
  if (kh == 1) return;

  {
    const float* p = &comb[qw][0][lane];
#pragma unroll
    for (int qg = 0; qg < 2; ++qg)
#pragma unroll
      for (int j2 = 0; j2 < 4; ++j2)
#pragma unroll
        for (int r = 0; r < 4; ++r)
          acc[qg][j2][r] += p[((qg * 4 + j2) * 4 + r) * 64];
    lsum[0] += p[32 * 64];
    lsum[1] += p[33 * 64];
  }

  // epilogue
#pragma unroll
  for (int qg = 0; qg < 2; ++qg) {
    float l = lsum[qg];
    l += __shfl_xor(l, 16);
    l += __shfl_xor(l, 32);
    float s = maskp[bb * T_ + qglob0 + qg * 16] / l;
#pragma unroll
    for (int r = 0; r < 4; ++r) {
      float bsc = __shfl(s, quad * 4 + r);
      int tq = q0 + qw * 32 + qg * 16 + quad * 4 + r;
#pragma unroll
      for (int j2 = 0; j2 < 4; ++j2)
        attn[((size_t)(bb * T_ + tq)) * D_ + hh * 64 + j2 * 16 + lm] = f2bf(acc[qg][j2][r] * bsc);
    }
  }
}

// --------------------------------------------- LN(x + attn_bf16) -> h1 f32+bf16
__global__ __launch_bounds__(256)
void ln_res_kernel(const float* __restrict__ xa, const unsigned short* __restrict__ attn,
                   const float* __restrict__ sc, const float* __restrict__ bi,
                   float* __restrict__ h, unsigned short* __restrict__ hb) {
  const int row = blockIdx.x, t = threadIdx.x;
  const int lane = t & 63, wid = t >> 6;
  size_t base = (size_t)row * D_ + t * 4;
  float4 a = *(const float4*)&xa[base];
  union { uint2 u; unsigned short s[4]; } au;
  au.u = *(const uint2*)&attn[base];
  float v0 = a.x + bf2f(au.s[0]), v1 = a.y + bf2f(au.s[1]);
  float v2 = a.z + bf2f(au.s[2]), v3 = a.w + bf2f(au.s[3]);
  float s1 = v0 + v1 + v2 + v3;
  float s2 = v0 * v0 + v1 * v1 + v2 * v2 + v3 * v3;
#pragma unroll
  for (int off = 32; off; off >>= 1) { s1 += __shfl_down(s1, off); s2 += __shfl_down(s2, off); }
  __shared__ float r1[4], r2[4];
  if (lane == 0) { r1[wid] = s1; r2[wid] = s2; }
  __syncthreads();
  s1 = r1[0] + r1[1] + r1[2] + r1[3];
  s2 = r2[0] + r2[1] + r2[2] + r2[3];
  float mean = s1 * (1.f / 1024.f);
  float var = s2 * (1.f / 1024.f) - mean * mean;
  float rstd = rsqrtf(var + 1e-5f);
  float4 sv = *(const float4*)&sc[t * 4];
  float4 bv = *(const float4*)&bi[t * 4];
  float o0 = (v0 - mean) * rstd * sv.x + bv.x;
  float o1 = (v1 - mean) * rstd * sv.y + bv.y;
  float o2 = (v2 - mean) * rstd * sv.z + bv.z;
  float o3 = (v3 - mean) * rstd * sv.w + bv.w;
  float4 ov = {o0, o1, o2, o3};
  *(float4*)&h[base] = ov;
  union { uint2 u; unsigned short s[4]; } ob;
  ob.s[0] = f2bf(o0); ob.s[1] = f2bf(o1); ob.s[2] = f2bf(o2); ob.s[3] = f2bf(o3);
  *(uint2*)&hb[base] = ob.u;
}

// --------------------------------------- out = LN(LN(h1+ffn,ln2),ln3)
__global__ __launch_bounds__(256)
void ln_double_kernel(const float* __restrict__ h1, const float* __restrict__ ffn,
                      const float* __restrict__ s2c, const float* __restrict__ b2c,
                      const float* __restrict__ s3c, const float* __restrict__ b3c,
                      float* __restrict__ out) {
  const int row = blockIdx.x, t = threadIdx.x;
  const int lane = t & 63, wid = t >> 6;
  size_t base = (size_t)row * D_ + t * 4;
  float4 a = *(const float4*)&h1[base];
  float4 b = *(const float4*)&ffn[base];
  float v0 = a.x + b.x, v1 = a.y + b.y, v2 = a.z + b.z, v3 = a.w + b.w;
  float s1 = v0 + v1 + v2 + v3;
  float s2 = v0 * v0 + v1 * v1 + v2 * v2 + v3 * v3;
#pragma unroll
  for (int off = 32; off; off >>= 1) { s1 += __shfl_down(s1, off); s2 += __shfl_down(s2, off); }
  __shared__ float ra[4], rb[4], rc[4], rd[4];
  if (lane == 0) { ra[wid] = s1; rb[wid] = s2; }
  __syncthreads();
  s1 = ra[0] + ra[1] + ra[2] + ra[3];
  s2 = rb[0] + rb[1] + rb[2] + rb[3];
  float mean = s1 * (1.f / 1024.f);
  float var = s2 * (1.f / 1024.f) - mean * mean;
  float rstd = rsqrtf(var + 1e-5f);
  float4 sv = *(const float4*)&s2c[t * 4];
  float4 bv = *(const float4*)&b2c[t * 4];
  float o0 = (v0 - mean) * rstd * sv.x + bv.x;
  float o1 = (v1 - mean) * rstd * sv.y + bv.y;
  float o2 = (v2 - mean) * rstd * sv.z + bv.z;
  float o3 = (v3 - mean) * rstd * sv.w + bv.w;
  float u1 = o0 + o1 + o2 + o3;
  float u2 = o0 * o0 + o1 * o1 + o2 * o2 + o3 * o3;
#pragma unroll
  for (int off = 32; off; off >>= 1) { u1 += __shfl_down(u1, off); u2 += __shfl_down(u2, off); }
  if (lane == 0) { rc[wid] = u1; rd[wid] = u2; }
  __syncthreads();
  u1 = rc[0] + rc[1] + rc[2] + rc[3];
  u2 = rd[0] + rd[1] + rd[2] + rd[3];
  float mean2 = u1 * (1.f / 1024.f);
  float var2 = u2 * (1.f / 1024.f) - mean2 * mean2;
  float rstd2 = rsqrtf(var2 + 1e-5f);
  float4 s3v = *(const float4*)&s3c[t * 4];
  float4 b3v = *(const float4*)&b3c[t * 4];
  float4 fo;
  fo.x = (o0 - mean2) * rstd2 * s3v.x + b3v.x;
  fo.y = (o1 - mean2) * rstd2 * s3v.y + b3v.y;
  fo.z = (o2 - mean2) * rstd2 * s3v.z + b3v.z;
  fo.w = (o3 - mean2) * rstd2 * s3v.w + b3v.w;
  *(float4*)&out[base] = fo;
}

// ------------------------------------------------------------------ launch
extern "C" void kernel_launch(void* const* d_in, const int* in_sizes, int n_in,
                              void* d_out, int out_size, void* d_ws, size_t ws_size,
                              hipStream_t stream) {
  (void)in_sizes; (void)n_in; (void)out_size; (void)ws_size;
  const float* x   = (const float*)d_in[0];
  const float* msk = (const float*)d_in[1];
  const float* wq  = (const float*)d_in[2];
  const float* wk  = (const float*)d_in[3];
  const float* wv  = (const float*)d_in[4];
  const float* w1  = (const float*)d_in[5];
  const float* b1  = (const float*)d_in[6];
  const float* w2  = (const float*)d_in[7];
  const float* b2  = (const float*)d_in[8];
  const float* l1s = (const float*)d_in[9];
  const float* l1b = (const float*)d_in[10];
  const float* l2s = (const float*)d_in[11];
  const float* l2b = (const float*)d_in[12];
  const float* l3s = (const float*)d_in[13];
  const float* l3b = (const float*)d_in[14];
  float* outp = (float*)d_out;

  char* ws = (char*)d_ws;
  unsigned short* xb   = (unsigned short*)(ws);                       // 8 MB
  unsigned short* wt   = (unsigned short*)(ws + ((size_t)8  << 20));  // 10 MB
  unsigned short* Qb   = (unsigned short*)(ws + ((size_t)18 << 20));  // 8 MB [B,H,T,DH]
  unsigned short* Kb   = (unsigned short*)(ws + ((size_t)26 << 20));  // 8 MB
  _Float16*       Vtg  = (_Float16*)(ws + ((size_t)34 << 20));        // 8 MB k-shuffled V^T
  unsigned short* attn = (unsigned short*)(ws + ((size_t)42 << 20));  // 8 MB bf16 [B,T,D]
  float* h1            = (float*)(ws + ((size_t)50 << 20));           // 16 MB
  unsigned short* h1b  = (unsigned short*)(ws + ((size_t)18 << 20));  // reuse Qb
  unsigned short* gb   = (unsigned short*)(ws + ((size_t)26 << 20));  // reuse Kb
  float* ffn           = (float*)(ws + ((size_t)34 << 20));           // reuse Vtg+attn

  prep_kernel<<<4096 + 1280, 256, 0, stream>>>((const float4*)x, xb,
                                               wq, wk, wv, w1, w2, wt);
  gemm_qkv<<<dim3(24, 32), 256, 0, stream>>>(xb, wt, Qb, Kb, Vtg);
  flash_attn<<<512, 512, 0, stream>>>(Qb, Kb, Vtg, msk, attn);
  ln_res_kernel<<<4096, 256, 0, stream>>>(x, attn, l1s, l1b, h1, h1b);
  gemm_ffn<1><<<dim3(8, 64), 256, 0, stream>>>(h1b, wt + (size_t)3 * 1024 * 1024, gb, nullptr, b1);
  gemm_ffn<2><<<dim3(8, 64), 256, 0, stream>>>(gb, wt + (size_t)4 * 1024 * 1024, nullptr, ffn, b2);
  ln_double_kernel<<<4096, 256, 0, stream>>>(h1, ffn, l2s, l2b, l3s, l3b, outp);
}

// Round 2
// 267.098 us; speedup vs baseline: 1.4272x; 1.4272x over previous
//
#include <hip/hip_runtime.h>
#include <stdint.h>

// B=4, T=1024, D=1024, H=16, DH=64. fp32 in/out, absmax thr 0.1.
// R10 vs R8 (R9 reverted — launch_bounds(512,4) forced 64 VGPR -> massive
// scratch spill, WRITE_SIZE 8->250MB, flash 50.8->188us):
//  - flash wave body identical to R8 (116 VGPR, launch_bounds(256), no cap).
//  - occupancy fix moved cross-block: 1024 blocks, bid bit3 = kh selects a
//    kb half-range. Fixed-shift exp2 softmax has no running max -> partials
//    add linearly. Each half writes UNNORMALIZED bf16 acc + fp32 lsum;
//    ln_res combines (a0+a1)*mask/(l0+l1). 4096 waves = 4/SIMD (was 2).
//  - workspace re-laid-out, stays within 66MB: lsums in dead xb slab,
//    h1 over dead Kb+Vtg, gb over dead aP0, ffn over dead aP1.

#define B_  4
#define T_  1024
#define D_  1024
#define H_  16
#define DH_ 64

typedef __attribute__((ext_vector_type(8))) short short8;
typedef __attribute__((ext_vector_type(4))) float floatx4;
typedef __attribute__((ext_vector_type(4))) _Float16 half4;

__device__ __forceinline__ unsigned short f2bf(float f) {
  union { float f; uint32_t u; } a; a.f = f;
  uint32_t r = a.u + 0x7FFFu + ((a.u >> 16) & 1u);
  return (unsigned short)(r >> 16);
}
__device__ __forceinline__ float bf2f(unsigned short u) {
  union { uint32_t u; float f; } a; a.u = ((uint32_t)u) << 16;
  return a.f;
}

#define GLD_LDS16(g, l) __builtin_amdgcn_global_load_lds( \
    (const __attribute__((address_space(1))) unsigned int*)(g), \
    (__attribute__((address_space(3))) unsigned int*)(l), 16, 0, 0)

// ---------------------------------------------- prep: cast x + transpose W
__global__ __launch_bounds__(256)
void prep_kernel(const float4* __restrict__ x4, unsigned short* __restrict__ xb,
                 const float* __restrict__ w0, const float* __restrict__ w1,
                 const float* __restrict__ w2, const float* __restrict__ w3,
                 const float* __restrict__ w4, unsigned short* __restrict__ dst_all) {
  const int t = threadIdx.x;
  if (blockIdx.x < 4096) {
    int idx = blockIdx.x * 256 + t;
    float4 v = x4[idx];
    union { uint2 u; unsigned short s[4]; } o;
    o.s[0] = f2bf(v.x); o.s[1] = f2bf(v.y); o.s[2] = f2bf(v.z); o.s[3] = f2bf(v.w);
    *(uint2*)&xb[(size_t)idx * 4] = o.u;
    return;
  }
  const int b = blockIdx.x - 4096;
  const int z = b >> 8, ky = (b >> 4) & 15, nx = b & 15;
  const float* src = (z == 0) ? w0 : (z == 1) ? w1 : (z == 2) ? w2 : (z == 3) ? w3 : w4;
  unsigned short* dst = dst_all + (size_t)z * D_ * D_;
  __shared__ __align__(16) unsigned short tile[64 * 72];
  const int k0 = ky * 64, n0 = nx * 64;
#pragma unroll
  for (int c = 0; c < 4; ++c) {
    int idx = c * 256 + t;
    int r = idx >> 4, cc = (idx & 15) << 2;
    float4 v = *(const float4*)&src[(size_t)(k0 + r) * D_ + n0 + cc];
    tile[(cc + 0) * 72 + r] = f2bf(v.x);
    tile[(cc + 1) * 72 + r] = f2bf(v.y);
    tile[(cc + 2) * 72 + r] = f2bf(v.z);
    tile[(cc + 3) * 72 + r] = f2bf(v.w);
  }
  __syncthreads();
  int rr = t >> 2, ck = (t & 3) << 4;
  uint4 v0 = *(const uint4*)&tile[rr * 72 + ck];
  uint4 v1 = *(const uint4*)&tile[rr * 72 + ck + 8];
  *(uint4*)&dst[(size_t)(n0 + rr) * D_ + k0 + ck] = v0;
  *(uint4*)&dst[(size_t)(n0 + rr) * D_ + k0 + ck + 8] = v1;
}

// ------------------------------------------------------------------ QKV GEMM
// Q pre-scaled by 0.125*log2(e); Q,K bf16 -> [B,H,T,DH]; V fp16 k-shuffled
// V^T [d][kb][quad][j][r] staged via LDS for coalesced stores.
__global__ __launch_bounds__(256, 2)
void gemm_qkv(const unsigned short* __restrict__ A,
              const unsigned short* __restrict__ Bt,
              unsigned short* __restrict__ oQ, unsigned short* __restrict__ oK,
              _Float16* __restrict__ oV) {
  const int K = 1024;
  __shared__ __align__(16) unsigned short As[128 * 32];
  __shared__ __align__(16) unsigned short Bs[128 * 32];
  __shared__ __align__(16) _Float16 Cs[2 * 64 * 136];
  const int t = threadIdx.x;
  const int lane = t & 63, w = t >> 6;
  const int quad = lane >> 4, lm = lane & 15;
  const int wm = w >> 1, wn = w & 1;
  const int m0 = blockIdx.y * 128, n0 = blockIdx.x * 128;
  const int arow = w * 32 + (lane >> 2), acol = (lane & 3) << 3;

  floatx4 acc[4][4];
#pragma unroll
  for (int i = 0; i < 4; ++i)
#pragma unroll
    for (int j = 0; j < 4; ++j) acc[i][j] = (floatx4){0.f, 0.f, 0.f, 0.f};

  for (int kt = 0; kt < K; kt += 32) {
    const unsigned short* ga = A + (size_t)(m0 + arow) * K + kt + acol;
    const unsigned short* gb = Bt + (size_t)(n0 + arow) * K + kt + acol;
    GLD_LDS16(ga, &As[(w * 32) * 32]);
    GLD_LDS16(ga + (size_t)16 * K, &As[(w * 32 + 16) * 32]);
    GLD_LDS16(gb, &Bs[(w * 32) * 32]);
    GLD_LDS16(gb + (size_t)16 * K, &Bs[(w * 32 + 16) * 32]);
    __syncthreads();
    short8 a[4], b[4];
#pragma unroll
    for (int i = 0; i < 4; ++i) a[i] = *(const short8*)&As[(wm * 64 + i * 16 + lm) * 32 + quad * 8];
#pragma unroll
    for (int j = 0; j < 4; ++j) b[j] = *(const short8*)&Bs[(wn * 64 + j * 16 + lm) * 32 + quad * 8];
#pragma unroll
    for (int i = 0; i < 4; ++i)
#pragma unroll
      for (int j = 0; j < 4; ++j)
        acc[i][j] = __builtin_amdgcn_mfma_f32_16x16x32_bf16(a[i], b[j], acc[i][j], 0, 0, 0);
    __syncthreads();
  }

  if (n0 < 2048) {
    unsigned short* p = (n0 < 1024) ? oQ : oK;
    const float qscale = (n0 < 1024) ? 0.18033688f : 1.0f;   // 0.125*log2(e)
#pragma unroll
    for (int i = 0; i < 4; ++i) {
      int gmb = m0 + wm * 64 + i * 16 + quad * 4;
#pragma unroll
      for (int j = 0; j < 4; ++j) {
        int gn = n0 + wn * 64 + j * 16 + lm;
        int nn = gn & 1023, hh = nn >> 6, dd = nn & 63;
#pragma unroll
        for (int r = 0; r < 4; ++r) {
          int gm = gmb + r;
          int bb = gm >> 10, tt = gm & 1023;
          p[(((size_t)bb * H_ + hh) * T_ + tt) * DH_ + dd] = f2bf(acc[i][j][r] * qscale);
        }
      }
    }
  } else {
#pragma unroll
    for (int i = 0; i < 4; ++i) {
#pragma unroll
      for (int j = 0; j < 4; ++j) {
        int gn = n0 + wn * 64 + j * 16 + lm;
        int hd = (gn >> 6) & 1, dd = gn & 63;
        int kperm = quad * 32 + (wm * 4 + i) * 4;
        union { _Float16 h[4]; uint2 u; } pk;
#pragma unroll
        for (int r = 0; r < 4; ++r) pk.h[r] = (_Float16)acc[i][j][r];
        *(uint2*)&Cs[((size_t)(hd * 64 + dd)) * 136 + kperm] = pk.u;
      }
    }
    __syncthreads();
    const int row = t >> 1, half = t & 1;
    const int hd = row >> 6, dd = row & 63;
    const int hh = ((n0 & 1023) >> 6) + hd;
    const int bb = m0 >> 10, kbg = (m0 >> 7) & 7;
    const _Float16* srcp = &Cs[(size_t)(hd * 64 + dd) * 136 + half * 64];
    _Float16* dstp = oV + ((((size_t)bb * H_ + hh) * DH_ + dd) * 8 + kbg) * 128 + half * 64;
#pragma unroll
    for (int g = 0; g < 8; ++g)
      *(uint4*)(dstp + g * 8) = *(const uint4*)(srcp + g * 8);
  }
}

// ------------------------------------------------------------ FFN GEMM 64x128
template <int MODE>
__global__ __launch_bounds__(256, 2)
void gemm_ffn(const unsigned short* __restrict__ A,
              const unsigned short* __restrict__ Bt,
              unsigned short* __restrict__ oBf, float* __restrict__ oF,
              const float* __restrict__ bias) {
  const int K = 1024, N = 1024;
  __shared__ __align__(16) unsigned short As[64 * 32];
  __shared__ __align__(16) unsigned short Bs[128 * 32];
  const int t = threadIdx.x;
  const int lane = t & 63, w = t >> 6;
  const int quad = lane >> 4, lm = lane & 15;
  const int wm = w >> 1, wn = w & 1;
  const int m0 = blockIdx.y * 64, n0 = blockIdx.x * 128;
  const int lrow = lane >> 2, lcol = (lane & 3) << 3;

  floatx4 acc[2][4];
#pragma unroll
  for (int i = 0; i < 2; ++i)
#pragma unroll
    for (int j = 0; j < 4; ++j) acc[i][j] = (floatx4){0.f, 0.f, 0.f, 0.f};

  for (int kt = 0; kt < K; kt += 32) {
    const unsigned short* ga = A + (size_t)(m0 + w * 16 + lrow) * K + kt + lcol;
    const unsigned short* gb = Bt + (size_t)(n0 + w * 32 + lrow) * K + kt + lcol;
    GLD_LDS16(ga, &As[(w * 16) * 32]);
    GLD_LDS16(gb, &Bs[(w * 32) * 32]);
    GLD_LDS16(gb + (size_t)16 * K, &Bs[(w * 32 + 16) * 32]);
    __syncthreads();
    short8 a[2], b[4];
#pragma unroll
    for (int i = 0; i < 2; ++i) a[i] = *(const short8*)&As[(wm * 32 + i * 16 + lm) * 32 + quad * 8];
#pragma unroll
    for (int j = 0; j < 4; ++j) b[j] = *(const short8*)&Bs[(wn * 64 + j * 16 + lm) * 32 + quad * 8];
#pragma unroll
    for (int i = 0; i < 2; ++i)
#pragma unroll
      for (int j = 0; j < 4; ++j)
        acc[i][j] = __builtin_amdgcn_mfma_f32_16x16x32_bf16(a[i], b[j], acc[i][j], 0, 0, 0);
    __syncthreads();
  }

#pragma unroll
  for (int i = 0; i < 2; ++i) {
    int gmb = m0 + wm * 32 + i * 16 + quad * 4;
#pragma unroll
    for (int j = 0; j < 4; ++j) {
      int gn = n0 + wn * 64 + j * 16 + lm;
      float bv = bias[gn];
#pragma unroll
      for (int r = 0; r < 4; ++r) {
        int gm = gmb + r;
        float v = acc[i][j][r] + bv;
        if (MODE == 1) {
          oBf[(size_t)gm * N + gn] = f2bf(fmaxf(v, 0.f));
        } else {
          oF[(size_t)gm * N + gn] = v;
        }
      }
    }
  }
}

// --------------------------------------------------------------- flash attn
// 1024 blocks x 256 thr; wave body IDENTICAL to R8 (116 VGPR, no LDS, no
// spill). bid bit3 = kh: each block computes a HALF of the kb range for its
// (head, qb). Fixed-shift exp2 softmax -> partials additive; each half
// writes unnormalized bf16 acc + fp32 row lsum; ln_res combines.
__global__ __launch_bounds__(256)
void flash_attn(const unsigned short* __restrict__ Qb,
                const unsigned short* __restrict__ Kb,
                const _Float16* __restrict__ Vtg,
                unsigned short* __restrict__ aP0, unsigned short* __restrict__ aP1,
                float* __restrict__ lP0, float* __restrict__ lP1) {
  const int t = threadIdx.x;
  const int lane = t & 63, w = t >> 6;
  const int quad = lane >> 4, lm = lane & 15;

  const int bid = blockIdx.x;               // 0..1023
  const int xcd = bid & 7;
  const int kh = (bid >> 3) & 1;
  const int qslot = (bid >> 4) & 7;
  const int hgrp = bid >> 7;                // 0..7
  const int head = hgrp * 8 + xcd;          // 0..63
  const int qh = qslot >> 1;
  const int qb = (qslot & 1) ? 7 - qh : qh; // 0,7,1,6,2,5,3,4
  const int hh = head & 15, bb = head >> 4;
  const int q0 = qb << 7;

  const size_t headoff = ((size_t)bb * H_ + hh) * T_ * DH_;
  const unsigned short* Qh = Qb + headoff;
  const unsigned short* Kh = Kb + headoff;
  const _Float16* Vh = Vtg + headoff;   // k-shuffled [d][kb][quad][j][r]

  short8 qf[2][2];
#pragma unroll
  for (int qg = 0; qg < 2; ++qg)
#pragma unroll
    for (int ks = 0; ks < 2; ++ks)
      qf[qg][ks] = *(const short8*)(Qh + (size_t)(q0 + w * 32 + qg * 16 + lm) * 64 + ks * 32 + quad * 8);

  float lsum[2] = {0.f, 0.f};
  floatx4 acc[2][4];
#pragma unroll
  for (int qg = 0; qg < 2; ++qg)
#pragma unroll
    for (int j2 = 0; j2 < 4; ++j2) acc[qg][j2] = (floatx4){0.f, 0.f, 0.f, 0.f};

  const int qglob0 = q0 + w * 32 + lm;
  const bool excl1 = (qglob0 + 16 == 1023);   // row-1023 lane (qg=1 only)
  const float MSHIFT = 14426.950408f;          // 10000*log2(e)

  const int kb_lo = (qb == 7 && w == 3) ? 0 : qb;
  const int cnt = 8 - kb_lo;
  const int halfc = (cnt + 1) >> 1;
  const int kb_begin = kh ? kb_lo + halfc : kb_lo;
  const int kb_end   = kh ? 8 : kb_lo + halfc;

  // prologue: K fragments for kb_begin
  short8 kf[8][2];
  if (kb_begin < kb_end) {
    const unsigned short* Kblk = Kh + (size_t)(kb_begin * 128) * 64;
#pragma unroll
    for (int j = 0; j < 8; ++j) {
      kf[j][0] = *(const short8*)(Kblk + (size_t)(j * 16 + lm) * 64 + quad * 8);
      kf[j][1] = *(const short8*)(Kblk + (size_t)(j * 16 + lm) * 64 + 32 + quad * 8);
    }
  }

  for (int kb = kb_begin; kb < kb_end; ++kb) {
    const int k0 = kb * 128;
    const bool need_mask = (kb <= qb);
    const bool has_next = (kb + 1 < kb_end);
    const unsigned short* Kn = Kh + (size_t)((kb + 1) * 128) * 64;

    // V loads for this kb (consumed in PV; hidden by S+softmax of j=0..)
    union { uint4 u[4]; _Float16 h[32]; } vf[4];
#pragma unroll
    for (int j2 = 0; j2 < 4; ++j2) {
      const _Float16* vp = Vh + ((size_t)(j2 * 16 + lm) * 8 + kb) * 128 + quad * 32;
#pragma unroll
      for (int g = 0; g < 4; ++g) vf[j2].u[g] = *(const uint4*)(vp + g * 8);
    }

#pragma unroll
    for (int j = 0; j < 8; ++j) {
      // S-MFMAs consume kf[j]
      floatx4 st[2];
#pragma unroll
      for (int qg = 0; qg < 2; ++qg) {
        floatx4 z = (floatx4){0.f, 0.f, 0.f, 0.f};
        z = __builtin_amdgcn_mfma_f32_16x16x32_bf16(kf[j][0], qf[qg][0], z, 0, 0, 0);
        st[qg] = __builtin_amdgcn_mfma_f32_16x16x32_bf16(kf[j][1], qf[qg][1], z, 0, 0, 0);
      }
      // rotate: prefetch kb+1's fragment j into kf[j] (lands ~7 j-steps later)
      if (has_next) {
        kf[j][0] = *(const short8*)(Kn + (size_t)(j * 16 + lm) * 64 + quad * 8);
        kf[j][1] = *(const short8*)(Kn + (size_t)(j * 16 + lm) * 64 + 32 + quad * 8);
      }
      // softmax j
      half4 pa[2];
#pragma unroll
      for (int qg = 0; qg < 2; ++qg) {
        const int qq = qglob0 + qg * 16;
        const bool skip = (qg == 1) && excl1;
#pragma unroll
        for (int r = 0; r < 4; ++r) {
          int kg = k0 + j * 16 + quad * 4 + r;
          float v = st[qg][r];
          if (need_mask && !skip && kg <= qq) v -= MSHIFT;
          float p = __builtin_amdgcn_exp2f(v);
          lsum[qg] += p;
          pa[qg][r] = (_Float16)p;
        }
      }
      // PV j
#pragma unroll
      for (int j2 = 0; j2 < 4; ++j2) {
        half4 vb;
#pragma unroll
        for (int r = 0; r < 4; ++r) vb[r] = vf[j2].h[j * 4 + r];
        acc[0][j2] = __builtin_amdgcn_mfma_f32_16x16x16f16(pa[0], vb, acc[0][j2], 0, 0, 0);
        acc[1][j2] = __builtin_amdgcn_mfma_f32_16x16x16f16(pa[1], vb, acc[1][j2], 0, 0, 0);
      }
    }
  }

  // epilogue: write UNNORMALIZED partials (no mask, no divide) + row lsums
  unsigned short* ap = kh ? aP1 : aP0;
  float* lp = kh ? lP1 : lP0;
#pragma unroll
  for (int qg = 0; qg < 2; ++qg) {
    float l = lsum[qg];
    l += __shfl_xor(l, 16);
    l += __shfl_xor(l, 32);
    if (quad == 0)
      lp[((size_t)bb * H_ + hh) * T_ + qglob0 + qg * 16] = l;
#pragma unroll
    for (int r = 0; r < 4; ++r) {
      int tq = q0 + w * 32 + qg * 16 + quad * 4 + r;
#pragma unroll
      for (int j2 = 0; j2 < 4; ++j2)
        ap[((size_t)(bb * T_ + tq)) * D_ + hh * 64 + j2 * 16 + lm] = f2bf(acc[qg][j2][r]);
    }
  }
}

// ---------------------- LN(x + (a0+a1)*mask/(l0+l1)) -> h1 f32+bf16
__global__ __launch_bounds__(256)
void ln_res_kernel(const float* __restrict__ xa,
                   const unsigned short* __restrict__ a0,
                   const unsigned short* __restrict__ a1,
                   const float* __restrict__ l0, const float* __restrict__ l1,
                   const float* __restrict__ mk,
                   const float* __restrict__ sc, const float* __restrict__ bi,
                   float* __restrict__ h, unsigned short* __restrict__ hb) {
  const int row = blockIdx.x, t = threadIdx.x;
  const int lane = t & 63, wid = t >> 6;
  const int bb = row >> 10, tt = row & 1023;
  const int hh = t >> 4;                 // head owning this thread's 4 d's
  size_t base = (size_t)row * D_ + t * 4;
  float4 a = *(const float4*)&xa[base];
  union { uint2 u; unsigned short s[4]; } u0, u1;
  u0.u = *(const uint2*)&a0[base];
  u1.u = *(const uint2*)&a1[base];
  size_t lidx = ((size_t)bb * H_ + hh) * T_ + tt;
  float l = l0[lidx] + l1[lidx];
  float s = mk[bb * T_ + tt] / l;
  float v0 = a.x + (bf2f(u0.s[0]) + bf2f(u1.s[0])) * s;
  float v1 = a.y + (bf2f(u0.s[1]) + bf2f(u1.s[1])) * s;
  float v2 = a.z + (bf2f(u0.s[2]) + bf2f(u1.s[2])) * s;
  float v3 = a.w + (bf2f(u0.s[3]) + bf2f(u1.s[3])) * s;
  float s1 = v0 + v1 + v2 + v3;
  float s2 = v0 * v0 + v1 * v1 + v2 * v2 + v3 * v3;
#pragma unroll
  for (int off = 32; off; off >>= 1) { s1 += __shfl_down(s1, off); s2 += __shfl_down(s2, off); }
  __shared__ float r1[4], r2[4];
  if (lane == 0) { r1[wid] = s1; r2[wid] = s2; }
  __syncthreads();
  s1 = r1[0] + r1[1] + r1[2] + r1[3];
  s2 = r2[0] + r2[1] + r2[2] + r2[3];
  float mean = s1 * (1.f / 1024.f);
  float var = s2 * (1.f / 1024.f) - mean * mean;
  float rstd = rsqrtf(var + 1e-5f);
  float4 sv = *(const float4*)&sc[t * 4];
  float4 bv = *(const float4*)&bi[t * 4];
  float o0 = (v0 - mean) * rstd * sv.x + bv.x;
  float o1 = (v1 - mean) * rstd * sv.y + bv.y;
  float o2 = (v2 - mean) * rstd * sv.z + bv.z;
  float o3 = (v3 - mean) * rstd * sv.w + bv.w;
  float4 ov = {o0, o1, o2, o3};
  *(float4*)&h[base] = ov;
  union { uint2 u; unsigned short s[4]; } ob;
  ob.s[0] = f2bf(o0); ob.s[1] = f2bf(o1); ob.s[2] = f2bf(o2); ob.s[3] = f2bf(o3);
  *(uint2*)&hb[base] = ob.u;
}

// --------------------------------------- out = LN(LN(h1+ffn,ln2),ln3)
__global__ __launch_bounds__(256)
void ln_double_kernel(const float* __restrict__ h1, const float* __restrict__ ffn,
                      const float* __restrict__ s2c, const float* __restrict__ b2c,
                      const float* __restrict__ s3c, const float* __restrict__ b3c,
                      float* __restrict__ out) {
  const int row = blockIdx.x, t = threadIdx.x;
  const int lane = t & 63, wid = t >> 6;
  size_t base = (size_t)row * D_ + t * 4;
  float4 a = *(const float4*)&h1[base];
  float4 b = *(const float4*)&ffn[base];
  float v0 = a.x + b.x, v1 = a.y + b.y, v2 = a.z + b.z, v3 = a.w + b.w;
  float s1 = v0 + v1 + v2 + v3;
  float s2 = v0 * v0 + v1 * v1 + v2 * v2 + v3 * v3;
#pragma unroll
  for (int off = 32; off; off >>= 1) { s1 += __shfl_down(s1, off); s2 += __shfl_down(s2, off); }
  __shared__ float ra[4], rb[4], rc[4], rd[4];
  if (lane == 0) { ra[wid] = s1; rb[wid] = s2; }
  __syncthreads();
  s1 = ra[0] + ra[1] + ra[2] + ra[3];
  s2 = rb[0] + rb[1] + rb[2] + rb[3];
  float mean = s1 * (1.f / 1024.f);
  float var = s2 * (1.f / 1024.f) - mean * mean;
  float rstd = rsqrtf(var + 1e-5f);
  float4 sv = *(const float4*)&s2c[t * 4];
  float4 bv = *(const float4*)&b2c[t * 4];
  float o0 = (v0 - mean) * rstd * sv.x + bv.x;
  float o1 = (v1 - mean) * rstd * sv.y + bv.y;
  float o2 = (v2 - mean) * rstd * sv.z + bv.z;
  float o3 = (v3 - mean) * rstd * sv.w + bv.w;
  float u1 = o0 + o1 + o2 + o3;
  float u2 = o0 * o0 + o1 * o1 + o2 * o2 + o3 * o3;
#pragma unroll
  for (int off = 32; off; off >>= 1) { u1 += __shfl_down(u1, off); u2 += __shfl_down(u2, off); }
  if (lane == 0) { rc[wid] = u1; rd[wid] = u2; }
  __syncthreads();
  u1 = rc[0] + rc[1] + rc[2] + rc[3];
  u2 = rd[0] + rd[1] + rd[2] + rd[3];
  float mean2 = u1 * (1.f / 1024.f);
  float var2 = u2 * (1.f / 1024.f) - mean2 * mean2;
  float rstd2 = rsqrtf(var2 + 1e-5f);
  float4 s3v = *(const float4*)&s3c[t * 4];
  float4 b3v = *(const float4*)&b3c[t * 4];
  float4 fo;
  fo.x = (o0 - mean2) * rstd2 * s3v.x + b3v.x;
  fo.y = (o1 - mean2) * rstd2 * s3v.y + b3v.y;
  fo.z = (o2 - mean2) * rstd2 * s3v.z + b3v.z;
  fo.w = (o3 - mean2) * rstd2 * s3v.w + b3v.w;
  *(float4*)&out[base] = fo;
}

// ------------------------------------------------------------------ launch
extern "C" void kernel_launch(void* const* d_in, const int* in_sizes, int n_in,
                              void* d_out, int out_size, void* d_ws, size_t ws_size,
                              hipStream_t stream) {
  (void)in_sizes; (void)n_in; (void)out_size; (void)ws_size;
  const float* x   = (const float*)d_in[0];
  const float* msk = (const float*)d_in[1];
  const float* wq  = (const float*)d_in[2];
  const float* wk  = (const float*)d_in[3];
  const float* wv  = (const float*)d_in[4];
  const float* w1  = (const float*)d_in[5];
  const float* b1  = (const float*)d_in[6];
  const float* w2  = (const float*)d_in[7];
  const float* b2  = (const float*)d_in[8];
  const float* l1s = (const float*)d_in[9];
  const float* l1b = (const float*)d_in[10];
  const float* l2s = (const float*)d_in[11];
  const float* l2b = (const float*)d_in[12];
  const float* l3s = (const float*)d_in[13];
  const float* l3b = (const float*)d_in[14];
  float* outp = (float*)d_out;

  char* ws = (char*)d_ws;
  // live through flash:  xb@0(8; lsums reuse after qkv) wt@8(10) Qb@18(8)
  //                      Kb@26(8) Vtg@34(8) aP0@42(8) aP1@50(8)   = 58MB
  // after flash:         h1b@18 (Qb dead), h1@26(16; Kb+Vtg dead),
  //                      gb@42 (aP0 dead), ffn@50(16; aP1 dead+tail) = 66MB
  unsigned short* xb   = (unsigned short*)(ws);
  unsigned short* wt   = (unsigned short*)(ws + ((size_t)8  << 20));
  unsigned short* Qb   = (unsigned short*)(ws + ((size_t)18 << 20));
  unsigned short* Kb   = (unsigned short*)(ws + ((size_t)26 << 20));
  _Float16*       Vtg  = (_Float16*)(ws + ((size_t)34 << 20));
  unsigned short* aP0  = (unsigned short*)(ws + ((size_t)42 << 20));
  unsigned short* aP1  = (unsigned short*)(ws + ((size_t)50 << 20));
  float* lP0           = (float*)(ws);
  float* lP1           = (float*)(ws + ((size_t)1 << 20));
  unsigned short* h1b  = (unsigned short*)(ws + ((size_t)18 << 20));
  float* h1            = (float*)(ws + ((size_t)26 << 20));
  unsigned short* gb   = (unsigned short*)(ws + ((size_t)42 << 20));
  float* ffn           = (float*)(ws + ((size_t)50 << 20));

  prep_kernel<<<4096 + 1280, 256, 0, stream>>>((const float4*)x, xb,
                                               wq, wk, wv, w1, w2, wt);
  gemm_qkv<<<dim3(24, 32), 256, 0, stream>>>(xb, wt, Qb, Kb, Vtg);
  flash_attn<<<1024, 256, 0, stream>>>(Qb, Kb, Vtg, aP0, aP1, lP0, lP1);
  ln_res_kernel<<<4096, 256, 0, stream>>>(x, aP0, aP1, lP0, lP1, msk,
                                          l1s, l1b, h1, h1b);
  gemm_ffn<1><<<dim3(8, 64), 256, 0, stream>>>(h1b, wt + (size_t)3 * 1024 * 1024, gb, nullptr, b1);
  gemm_ffn<2><<<dim3(8, 64), 256, 0, stream>>>(gb, wt + (size_t)4 * 1024 * 1024, nullptr, ffn, b2);
  ln_double_kernel<<<4096, 256, 0, stream>>>(h1, ffn, l2s, l2b, l3s, l3b, outp);
}

// Round 3
// 262.205 us; speedup vs baseline: 1.4538x; 1.0187x over previous
//
#include <hip/hip_runtime.h>
#include <stdint.h>

// B=4, T=1024, D=1024, H=16, DH=64. fp32 in/out, absmax thr 0.1.
// R11 = R8 body exactly, with ONE change in flash_attn: the bid decode.
// R8 put the 8 qb-blocks of a head on 8 different XCDs (bid&7=qb) -> every
// XCD re-fetched the same K/V panels from HBM (FETCH 49MB, 42us of 50.8us).
// R10 proved the fix (bid&7=head%8 -> FETCH 12.4MB) but bundled it with a
// harmful kb-split (doubled per-block prologue/epilogue overhead, 68us).
// R11 unbundles: R8's full-range 8-trip blocks + R10's XCD head mapping.
// Per-XCD working set = 8 heads x (Q+K+V) ~ 3MB < 4MB L2; all 512 blocks
// co-resident (2/CU) so reuse is temporal within the dispatch.

#define B_  4
#define T_  1024
#define D_  1024
#define H_  16
#define DH_ 64

typedef __attribute__((ext_vector_type(8))) short short8;
typedef __attribute__((ext_vector_type(4))) float floatx4;
typedef __attribute__((ext_vector_type(4))) _Float16 half4;

__device__ __forceinline__ unsigned short f2bf(float f) {
  union { float f; uint32_t u; } a; a.f = f;
  uint32_t r = a.u + 0x7FFFu + ((a.u >> 16) & 1u);
  return (unsigned short)(r >> 16);
}
__device__ __forceinline__ float bf2f(unsigned short u) {
  union { uint32_t u; float f; } a; a.u = ((uint32_t)u) << 16;
  return a.f;
}

#define GLD_LDS16(g, l) __builtin_amdgcn_global_load_lds( \
    (const __attribute__((address_space(1))) unsigned int*)(g), \
    (__attribute__((address_space(3))) unsigned int*)(l), 16, 0, 0)

// ---------------------------------------------- prep: cast x + transpose W
__global__ __launch_bounds__(256)
void prep_kernel(const float4* __restrict__ x4, unsigned short* __restrict__ xb,
                 const float* __restrict__ w0, const float* __restrict__ w1,
                 const float* __restrict__ w2, const float* __restrict__ w3,
                 const float* __restrict__ w4, unsigned short* __restrict__ dst_all) {
  const int t = threadIdx.x;
  if (blockIdx.x < 4096) {
    int idx = blockIdx.x * 256 + t;
    float4 v = x4[idx];
    union { uint2 u; unsigned short s[4]; } o;
    o.s[0] = f2bf(v.x); o.s[1] = f2bf(v.y); o.s[2] = f2bf(v.z); o.s[3] = f2bf(v.w);
    *(uint2*)&xb[(size_t)idx * 4] = o.u;
    return;
  }
  const int b = blockIdx.x - 4096;
  const int z = b >> 8, ky = (b >> 4) & 15, nx = b & 15;
  const float* src = (z == 0) ? w0 : (z == 1) ? w1 : (z == 2) ? w2 : (z == 3) ? w3 : w4;
  unsigned short* dst = dst_all + (size_t)z * D_ * D_;
  __shared__ __align__(16) unsigned short tile[64 * 72];
  const int k0 = ky * 64, n0 = nx * 64;
#pragma unroll
  for (int c = 0; c < 4; ++c) {
    int idx = c * 256 + t;
    int r = idx >> 4, cc = (idx & 15) << 2;
    float4 v = *(const float4*)&src[(size_t)(k0 + r) * D_ + n0 + cc];
    tile[(cc + 0) * 72 + r] = f2bf(v.x);
    tile[(cc + 1) * 72 + r] = f2bf(v.y);
    tile[(cc + 2) * 72 + r] = f2bf(v.z);
    tile[(cc + 3) * 72 + r] = f2bf(v.w);
  }
  __syncthreads();
  int rr = t >> 2, ck = (t & 3) << 4;
  uint4 v0 = *(const uint4*)&tile[rr * 72 + ck];
  uint4 v1 = *(const uint4*)&tile[rr * 72 + ck + 8];
  *(uint4*)&dst[(size_t)(n0 + rr) * D_ + k0 + ck] = v0;
  *(uint4*)&dst[(size_t)(n0 + rr) * D_ + k0 + ck + 8] = v1;
}

// ------------------------------------------------------------------ QKV GEMM
// Q pre-scaled by 0.125*log2(e); Q,K bf16 -> [B,H,T,DH]; V fp16 k-shuffled
// V^T [d][kb][quad][j][r] staged via LDS for coalesced stores.
__global__ __launch_bounds__(256, 2)
void gemm_qkv(const unsigned short* __restrict__ A,
              const unsigned short* __restrict__ Bt,
              unsigned short* __restrict__ oQ, unsigned short* __restrict__ oK,
              _Float16* __restrict__ oV) {
  const int K = 1024;
  __shared__ __align__(16) unsigned short As[128 * 32];
  __shared__ __align__(16) unsigned short Bs[128 * 32];
  __shared__ __align__(16) _Float16 Cs[2 * 64 * 136];
  const int t = threadIdx.x;
  const int lane = t & 63, w = t >> 6;
  const int quad = lane >> 4, lm = lane & 15;
  const int wm = w >> 1, wn = w & 1;
  const int m0 = blockIdx.y * 128, n0 = blockIdx.x * 128;
  const int arow = w * 32 + (lane >> 2), acol = (lane & 3) << 3;

  floatx4 acc[4][4];
#pragma unroll
  for (int i = 0; i < 4; ++i)
#pragma unroll
    for (int j = 0; j < 4; ++j) acc[i][j] = (floatx4){0.f, 0.f, 0.f, 0.f};

  for (int kt = 0; kt < K; kt += 32) {
    const unsigned short* ga = A + (size_t)(m0 + arow) * K + kt + acol;
    const unsigned short* gb = Bt + (size_t)(n0 + arow) * K + kt + acol;
    GLD_LDS16(ga, &As[(w * 32) * 32]);
    GLD_LDS16(ga + (size_t)16 * K, &As[(w * 32 + 16) * 32]);
    GLD_LDS16(gb, &Bs[(w * 32) * 32]);
    GLD_LDS16(gb + (size_t)16 * K, &Bs[(w * 32 + 16) * 32]);
    __syncthreads();
    short8 a[4], b[4];
#pragma unroll
    for (int i = 0; i < 4; ++i) a[i] = *(const short8*)&As[(wm * 64 + i * 16 + lm) * 32 + quad * 8];
#pragma unroll
    for (int j = 0; j < 4; ++j) b[j] = *(const short8*)&Bs[(wn * 64 + j * 16 + lm) * 32 + quad * 8];
#pragma unroll
    for (int i = 0; i < 4; ++i)
#pragma unroll
      for (int j = 0; j < 4; ++j)
        acc[i][j] = __builtin_amdgcn_mfma_f32_16x16x32_bf16(a[i], b[j], acc[i][j], 0, 0, 0);
    __syncthreads();
  }

  if (n0 < 2048) {
    unsigned short* p = (n0 < 1024) ? oQ : oK;
    const float qscale = (n0 < 1024) ? 0.18033688f : 1.0f;   // 0.125*log2(e)
#pragma unroll
    for (int i = 0; i < 4; ++i) {
      int gmb = m0 + wm * 64 + i * 16 + quad * 4;
#pragma unroll
      for (int j = 0; j < 4; ++j) {
        int gn = n0 + wn * 64 + j * 16 + lm;
        int nn = gn & 1023, hh = nn >> 6, dd = nn & 63;
#pragma unroll
        for (int r = 0; r < 4; ++r) {
          int gm = gmb + r;
          int bb = gm >> 10, tt = gm & 1023;
          p[(((size_t)bb * H_ + hh) * T_ + tt) * DH_ + dd] = f2bf(acc[i][j][r] * qscale);
        }
      }
    }
  } else {
#pragma unroll
    for (int i = 0; i < 4; ++i) {
#pragma unroll
      for (int j = 0; j < 4; ++j) {
        int gn = n0 + wn * 64 + j * 16 + lm;
        int hd = (gn >> 6) & 1, dd = gn & 63;
        int kperm = quad * 32 + (wm * 4 + i) * 4;
        union { _Float16 h[4]; uint2 u; } pk;
#pragma unroll
        for (int r = 0; r < 4; ++r) pk.h[r] = (_Float16)acc[i][j][r];
        *(uint2*)&Cs[((size_t)(hd * 64 + dd)) * 136 + kperm] = pk.u;
      }
    }
    __syncthreads();
    const int row = t >> 1, half = t & 1;
    const int hd = row >> 6, dd = row & 63;
    const int hh = ((n0 & 1023) >> 6) + hd;
    const int bb = m0 >> 10, kbg = (m0 >> 7) & 7;
    const _Float16* srcp = &Cs[(size_t)(hd * 64 + dd) * 136 + half * 64];
    _Float16* dstp = oV + ((((size_t)bb * H_ + hh) * DH_ + dd) * 8 + kbg) * 128 + half * 64;
#pragma unroll
    for (int g = 0; g < 8; ++g)
      *(uint4*)(dstp + g * 8) = *(const uint4*)(srcp + g * 8);
  }
}

// ------------------------------------------------------------ FFN GEMM 64x128
template <int MODE>
__global__ __launch_bounds__(256, 2)
void gemm_ffn(const unsigned short* __restrict__ A,
              const unsigned short* __restrict__ Bt,
              unsigned short* __restrict__ oBf, float* __restrict__ oF,
              const float* __restrict__ bias) {
  const int K = 1024, N = 1024;
  __shared__ __align__(16) unsigned short As[64 * 32];
  __shared__ __align__(16) unsigned short Bs[128 * 32];
  const int t = threadIdx.x;
  const int lane = t & 63, w = t >> 6;
  const int quad = lane >> 4, lm = lane & 15;
  const int wm = w >> 1, wn = w & 1;
  const int m0 = blockIdx.y * 64, n0 = blockIdx.x * 128;
  const int lrow = lane >> 2, lcol = (lane & 3) << 3;

  floatx4 acc[2][4];
#pragma unroll
  for (int i = 0; i < 2; ++i)
#pragma unroll
    for (int j = 0; j < 4; ++j) acc[i][j] = (floatx4){0.f, 0.f, 0.f, 0.f};

  for (int kt = 0; kt < K; kt += 32) {
    const unsigned short* ga = A + (size_t)(m0 + w * 16 + lrow) * K + kt + lcol;
    const unsigned short* gb = Bt + (size_t)(n0 + w * 32 + lrow) * K + kt + lcol;
    GLD_LDS16(ga, &As[(w * 16) * 32]);
    GLD_LDS16(gb, &Bs[(w * 32) * 32]);
    GLD_LDS16(gb + (size_t)16 * K, &Bs[(w * 32 + 16) * 32]);
    __syncthreads();
    short8 a[2], b[4];
#pragma unroll
    for (int i = 0; i < 2; ++i) a[i] = *(const short8*)&As[(wm * 32 + i * 16 + lm) * 32 + quad * 8];
#pragma unroll
    for (int j = 0; j < 4; ++j) b[j] = *(const short8*)&Bs[(wn * 64 + j * 16 + lm) * 32 + quad * 8];
#pragma unroll
    for (int i = 0; i < 2; ++i)
#pragma unroll
      for (int j = 0; j < 4; ++j)
        acc[i][j] = __builtin_amdgcn_mfma_f32_16x16x32_bf16(a[i], b[j], acc[i][j], 0, 0, 0);
    __syncthreads();
  }

#pragma unroll
  for (int i = 0; i < 2; ++i) {
    int gmb = m0 + wm * 32 + i * 16 + quad * 4;
#pragma unroll
    for (int j = 0; j < 4; ++j) {
      int gn = n0 + wn * 64 + j * 16 + lm;
      float bv = bias[gn];
#pragma unroll
      for (int r = 0; r < 4; ++r) {
        int gm = gmb + r;
        float v = acc[i][j][r] + bv;
        if (MODE == 1) {
          oBf[(size_t)gm * N + gn] = f2bf(fmaxf(v, 0.f));
        } else {
          oF[(size_t)gm * N + gn] = v;
        }
      }
    }
  }
}

// --------------------------------------------------------------- flash attn
// 512 blocks x 256 thr; R8 body. bid decode: bid&7 = head%8 so all 8
// qb-blocks of a head land on ONE XCD (K/V panels L2-resident; R10 measured
// FETCH 49MB->12.4MB with this mapping). qslot interleaved 0,7,1,6,...
// pairs long+short blocks in dispatch order. Rotating per-j K-prefetch.
// Wave 3 of qb==7 blocks loops kb=0..7 with row 1023 never masked.
__global__ __launch_bounds__(256)
void flash_attn(const unsigned short* __restrict__ Qb,
                const unsigned short* __restrict__ Kb,
                const _Float16* __restrict__ Vtg,
                const float* __restrict__ maskp,
                unsigned short* __restrict__ attn) {
  const int t = threadIdx.x;
  const int lane = t & 63, w = t >> 6;
  const int quad = lane >> 4, lm = lane & 15;

  const int bid = blockIdx.x;               // 0..511
  const int xcd = bid & 7;
  const int qslot = (bid >> 3) & 7;
  const int hgrp = bid >> 6;                // 0..7
  const int head = hgrp * 8 + xcd;          // 0..63
  const int qh = qslot >> 1;
  const int qb = (qslot & 1) ? 7 - qh : qh; // 0,7,1,6,2,5,3,4
  const int hh = head & 15, bb = head >> 4;
  const int q0 = qb << 7;

  const size_t headoff = ((size_t)bb * H_ + hh) * T_ * DH_;
  const unsigned short* Qh = Qb + headoff;
  const unsigned short* Kh = Kb + headoff;
  const _Float16* Vh = Vtg + headoff;   // k-shuffled [d][kb][quad][j][r]

  short8 qf[2][2];
#pragma unroll
  for (int qg = 0; qg < 2; ++qg)
#pragma unroll
    for (int ks = 0; ks < 2; ++ks)
      qf[qg][ks] = *(const short8*)(Qh + (size_t)(q0 + w * 32 + qg * 16 + lm) * 64 + ks * 32 + quad * 8);

  float lsum[2] = {0.f, 0.f};
  floatx4 acc[2][4];
#pragma unroll
  for (int qg = 0; qg < 2; ++qg)
#pragma unroll
    for (int j2 = 0; j2 < 4; ++j2) acc[qg][j2] = (floatx4){0.f, 0.f, 0.f, 0.f};

  const int qglob0 = q0 + w * 32 + lm;
  const bool excl1 = (qglob0 + 16 == 1023);   // row-1023 lane (qg=1 only)
  const float MSHIFT = 14426.950408f;          // 10000*log2(e)

  const int kb_lo = (qb == 7 && w == 3) ? 0 : qb;

  // prologue: K fragments for kb_lo
  short8 kf[8][2];
  {
    const unsigned short* Kblk = Kh + (size_t)(kb_lo * 128) * 64;
#pragma unroll
    for (int j = 0; j < 8; ++j) {
      kf[j][0] = *(const short8*)(Kblk + (size_t)(j * 16 + lm) * 64 + quad * 8);
      kf[j][1] = *(const short8*)(Kblk + (size_t)(j * 16 + lm) * 64 + 32 + quad * 8);
    }
  }

  for (int kb = kb_lo; kb < 8; ++kb) {
    const int k0 = kb * 128;
    const bool need_mask = (kb <= qb);
    const bool has_next = (kb + 1 < 8);
    const unsigned short* Kn = Kh + (size_t)((kb + 1) * 128) * 64;

    // V loads for this kb (consumed in PV; hidden by S+softmax of j=0..)
    union { uint4 u[4]; _Float16 h[32]; } vf[4];
#pragma unroll
    for (int j2 = 0; j2 < 4; ++j2) {
      const _Float16* vp = Vh + ((size_t)(j2 * 16 + lm) * 8 + kb) * 128 + quad * 32;
#pragma unroll
      for (int g = 0; g < 4; ++g) vf[j2].u[g] = *(const uint4*)(vp + g * 8);
    }

#pragma unroll
    for (int j = 0; j < 8; ++j) {
      // S-MFMAs consume kf[j]
      floatx4 st[2];
#pragma unroll
      for (int qg = 0; qg < 2; ++qg) {
        floatx4 z = (floatx4){0.f, 0.f, 0.f, 0.f};
        z = __builtin_amdgcn_mfma_f32_16x16x32_bf16(kf[j][0], qf[qg][0], z, 0, 0, 0);
        st[qg] = __builtin_amdgcn_mfma_f32_16x16x32_bf16(kf[j][1], qf[qg][1], z, 0, 0, 0);
      }
      // rotate: prefetch kb+1's fragment j into kf[j] (lands ~7 j-steps later)
      if (has_next) {
        kf[j][0] = *(const short8*)(Kn + (size_t)(j * 16 + lm) * 64 + quad * 8);
        kf[j][1] = *(const short8*)(Kn + (size_t)(j * 16 + lm) * 64 + 32 + quad * 8);
      }
      // softmax j
      half4 pa[2];
#pragma unroll
      for (int qg = 0; qg < 2; ++qg) {
        const int qq = qglob0 + qg * 16;
        const bool skip = (qg == 1) && excl1;
#pragma unroll
        for (int r = 0; r < 4; ++r) {
          int kg = k0 + j * 16 + quad * 4 + r;
          float v = st[qg][r];
          if (need_mask && !skip && kg <= qq) v -= MSHIFT;
          float p = __builtin_amdgcn_exp2f(v);
          lsum[qg] += p;
          pa[qg][r] = (_Float16)p;
        }
      }
      // PV j
#pragma unroll
      for (int j2 = 0; j2 < 4; ++j2) {
        half4 vb;
#pragma unroll
        for (int r = 0; r < 4; ++r) vb[r] = vf[j2].h[j * 4 + r];
        acc[0][j2] = __builtin_amdgcn_mfma_f32_16x16x16f16(pa[0], vb, acc[0][j2], 0, 0, 0);
        acc[1][j2] = __builtin_amdgcn_mfma_f32_16x16x16f16(pa[1], vb, acc[1][j2], 0, 0, 0);
      }
    }
  }

  // epilogue
#pragma unroll
  for (int qg = 0; qg < 2; ++qg) {
    float l = lsum[qg];
    l += __shfl_xor(l, 16);
    l += __shfl_xor(l, 32);
    float s = maskp[bb * T_ + qglob0 + qg * 16] / l;
#pragma unroll
    for (int r = 0; r < 4; ++r) {
      float bsc = __shfl(s, quad * 4 + r);
      int tq = q0 + w * 32 + qg * 16 + quad * 4 + r;
#pragma unroll
      for (int j2 = 0; j2 < 4; ++j2)
        attn[((size_t)(bb * T_ + tq)) * D_ + hh * 64 + j2 * 16 + lm] = f2bf(acc[qg][j2][r] * bsc);
    }
  }
}

// --------------------------------------------- LN(x + attn_bf16) -> h1 f32+bf16
__global__ __launch_bounds__(256)
void ln_res_kernel(const float* __restrict__ xa, const unsigned short* __restrict__ attn,
                   const float* __restrict__ sc, const float* __restrict__ bi,
                   float* __restrict__ h, unsigned short* __restrict__ hb) {
  const int row = blockIdx.x, t = threadIdx.x;
  const int lane = t & 63, wid = t >> 6;
  size_t base = (size_t)row * D_ + t * 4;
  float4 a = *(const float4*)&xa[base];
  union { uint2 u; unsigned short s[4]; } au;
  au.u = *(const uint2*)&attn[base];
  float v0 = a.x + bf2f(au.s[0]), v1 = a.y + bf2f(au.s[1]);
  float v2 = a.z + bf2f(au.s[2]), v3 = a.w + bf2f(au.s[3]);
  float s1 = v0 + v1 + v2 + v3;
  float s2 = v0 * v0 + v1 * v1 + v2 * v2 + v3 * v3;
#pragma unroll
  for (int off = 32; off; off >>= 1) { s1 += __shfl_down(s1, off); s2 += __shfl_down(s2, off); }
  __shared__ float r1[4], r2[4];
  if (lane == 0) { r1[wid] = s1; r2[wid] = s2; }
  __syncthreads();
  s1 = r1[0] + r1[1] + r1[2] + r1[3];
  s2 = r2[0] + r2[1] + r2[2] + r2[3];
  float mean = s1 * (1.f / 1024.f);
  float var = s2 * (1.f / 1024.f) - mean * mean;
  float rstd = rsqrtf(var + 1e-5f);
  float4 sv = *(const float4*)&sc[t * 4];
  float4 bv = *(const float4*)&bi[t * 4];
  float o0 = (v0 - mean) * rstd * sv.x + bv.x;
  float o1 = (v1 - mean) * rstd * sv.y + bv.y;
  float o2 = (v2 - mean) * rstd * sv.z + bv.z;
  float o3 = (v3 - mean) * rstd * sv.w + bv.w;
  float4 ov = {o0, o1, o2, o3};
  *(float4*)&h[base] = ov;
  union { uint2 u; unsigned short s[4]; } ob;
  ob.s[0] = f2bf(o0); ob.s[1] = f2bf(o1); ob.s[2] = f2bf(o2); ob.s[3] = f2bf(o3);
  *(uint2*)&hb[base] = ob.u;
}

// --------------------------------------- out = LN(LN(h1+ffn,ln2),ln3)
__global__ __launch_bounds__(256)
void ln_double_kernel(const float* __restrict__ h1, const float* __restrict__ ffn,
                      const float* __restrict__ s2c, const float* __restrict__ b2c,
                      const float* __restrict__ s3c, const float* __restrict__ b3c,
                      float* __restrict__ out) {
  const int row = blockIdx.x, t = threadIdx.x;
  const int lane = t & 63, wid = t >> 6;
  size_t base = (size_t)row * D_ + t * 4;
  float4 a = *(const float4*)&h1[base];
  float4 b = *(const float4*)&ffn[base];
  float v0 = a.x + b.x, v1 = a.y + b.y, v2 = a.z + b.z, v3 = a.w + b.w;
  float s1 = v0 + v1 + v2 + v3;
  float s2 = v0 * v0 + v1 * v1 + v2 * v2 + v3 * v3;
#pragma unroll
  for (int off = 32; off; off >>= 1) { s1 += __shfl_down(s1, off); s2 += __shfl_down(s2, off); }
  __shared__ float ra[4], rb[4], rc[4], rd[4];
  if (lane == 0) { ra[wid] = s1; rb[wid] = s2; }
  __syncthreads();
  s1 = ra[0] + ra[1] + ra[2] + ra[3];
  s2 = rb[0] + rb[1] + rb[2] + rb[3];
  float mean = s1 * (1.f / 1024.f);
  float var = s2 * (1.f / 1024.f) - mean * mean;
  float rstd = rsqrtf(var + 1e-5f);
  float4 sv = *(const float4*)&s2c[t * 4];
  float4 bv = *(const float4*)&b2c[t * 4];
  float o0 = (v0 - mean) * rstd * sv.x + bv.x;
  float o1 = (v1 - mean) * rstd * sv.y + bv.y;
  float o2 = (v2 - mean) * rstd * sv.z + bv.z;
  float o3 = (v3 - mean) * rstd * sv.w + bv.w;
  float u1 = o0 + o1 + o2 + o3;
  float u2 = o0 * o0 + o1 * o1 + o2 * o2 + o3 * o3;
#pragma unroll
  for (int off = 32; off; off >>= 1) { u1 += __shfl_down(u1, off); u2 += __shfl_down(u2, off); }
  if (lane == 0) { rc[wid] = u1; rd[wid] = u2; }
  __syncthreads();
  u1 = rc[0] + rc[1] + rc[2] + rc[3];
  u2 = rd[0] + rd[1] + rd[2] + rd[3];
  float mean2 = u1 * (1.f / 1024.f);
  float var2 = u2 * (1.f / 1024.f) - mean2 * mean2;
  float rstd2 = rsqrtf(var2 + 1e-5f);
  float4 s3v = *(const float4*)&s3c[t * 4];
  float4 b3v = *(const float4*)&b3c[t * 4];
  float4 fo;
  fo.x = (o0 - mean2) * rstd2 * s3v.x + b3v.x;
  fo.y = (o1 - mean2) * rstd2 * s3v.y + b3v.y;
  fo.z = (o2 - mean2) * rstd2 * s3v.z + b3v.z;
  fo.w = (o3 - mean2) * rstd2 * s3v.w + b3v.w;
  *(float4*)&out[base] = fo;
}

// ------------------------------------------------------------------ launch
extern "C" void kernel_launch(void* const* d_in, const int* in_sizes, int n_in,
                              void* d_out, int out_size, void* d_ws, size_t ws_size,
                              hipStream_t stream) {
  (void)in_sizes; (void)n_in; (void)out_size; (void)ws_size;
  const float* x   = (const float*)d_in[0];
  const float* msk = (const float*)d_in[1];
  const float* wq  = (const float*)d_in[2];
  const float* wk  = (const float*)d_in[3];
  const float* wv  = (const float*)d_in[4];
  const float* w1  = (const float*)d_in[5];
  const float* b1  = (const float*)d_in[6];
  const float* w2  = (const float*)d_in[7];
  const float* b2  = (const float*)d_in[8];
  const float* l1s = (const float*)d_in[9];
  const float* l1b = (const float*)d_in[10];
  const float* l2s = (const float*)d_in[11];
  const float* l2b = (const float*)d_in[12];
  const float* l3s = (const float*)d_in[13];
  const float* l3b = (const float*)d_in[14];
  float* outp = (float*)d_out;

  char* ws = (char*)d_ws;
  unsigned short* xb   = (unsigned short*)(ws);                       // 8 MB
  unsigned short* wt   = (unsigned short*)(ws + ((size_t)8  << 20));  // 10 MB
  unsigned short* Qb   = (unsigned short*)(ws + ((size_t)18 << 20));  // 8 MB [B,H,T,DH]
  unsigned short* Kb   = (unsigned short*)(ws + ((size_t)26 << 20));  // 8 MB
  _Float16*       Vtg  = (_Float16*)(ws + ((size_t)34 << 20));        // 8 MB k-shuffled V^T
  unsigned short* attn = (unsigned short*)(ws + ((size_t)42 << 20));  // 8 MB bf16 [B,T,D]
  float* h1            = (float*)(ws + ((size_t)50 << 20));           // 16 MB
  unsigned short* h1b  = (unsigned short*)(ws + ((size_t)18 << 20));  // reuse Qb
  unsigned short* gb   = (unsigned short*)(ws + ((size_t)26 << 20));  // reuse Kb
  float* ffn           = (float*)(ws + ((size_t)34 << 20));           // reuse Vtg+attn

  prep_kernel<<<4096 + 1280, 256, 0, stream>>>((const float4*)x, xb,
                                               wq, wk, wv, w1, w2, wt);
  gemm_qkv<<<dim3(24, 32), 256, 0, stream>>>(xb, wt, Qb, Kb, Vtg);
  flash_attn<<<512, 256, 0, stream>>>(Qb, Kb, Vtg, msk, attn);
  ln_res_kernel<<<4096, 256, 0, stream>>>(x, attn, l1s, l1b, h1, h1b);
  gemm_ffn<1><<<dim3(8, 64), 256, 0, stream>>>(h1b, wt + (size_t)3 * 1024 * 1024, gb, nullptr, b1);
  gemm_ffn<2><<<dim3(8, 64), 256, 0, stream>>>(gb, wt + (size_t)4 * 1024 * 1024, nullptr, ffn, b2);
  ln_double_kernel<<<4096, 256, 0, stream>>>(h1, ffn, l2s, l2b, l3s, l3b, outp);
}

// Round 4
// 246.936 us; speedup vs baseline: 1.5437x; 1.0618x over previous
//
#include <hip/hip_runtime.h>
#include <stdint.h>

// B=4, T=1024, D=1024, H=16, DH=64. fp32 in/out, absmax thr 0.1.
// R12 vs R11: fix the co-residency pairing R11 broke.
// With 512 blocks at 2/CU, bid and bid+256 are co-resident on one CU.
// R8 made them complementary in qb (8-trip paired with 1-trip -> 9
// trips/CU); R11's decode gave them the SAME qb (16-trip worst CU ->
// 67us, vs 50.8 R8). R12 keeps R11's XCD head mapping (bid&7=head%8,
// FETCH 49->14MB, K/V L2-resident) and moves the complement back to
// bid bit 8: qpair in bits 6-7, qb = hi ? 7-qpair : qpair. Now the two
// co-resident blocks are the SAME head with complementary kb ranges:
// balanced 9 trips/CU AND shared K/V in L1/L2.

#define B_  4
#define T_  1024
#define D_  1024
#define H_  16
#define DH_ 64

typedef __attribute__((ext_vector_type(8))) short short8;
typedef __attribute__((ext_vector_type(4))) float floatx4;
typedef __attribute__((ext_vector_type(4))) _Float16 half4;

__device__ __forceinline__ unsigned short f2bf(float f) {
  union { float f; uint32_t u; } a; a.f = f;
  uint32_t r = a.u + 0x7FFFu + ((a.u >> 16) & 1u);
  return (unsigned short)(r >> 16);
}
__device__ __forceinline__ float bf2f(unsigned short u) {
  union { uint32_t u; float f; } a; a.u = ((uint32_t)u) << 16;
  return a.f;
}

#define GLD_LDS16(g, l) __builtin_amdgcn_global_load_lds( \
    (const __attribute__((address_space(1))) unsigned int*)(g), \
    (__attribute__((address_space(3))) unsigned int*)(l), 16, 0, 0)

// ---------------------------------------------- prep: cast x + transpose W
__global__ __launch_bounds__(256)
void prep_kernel(const float4* __restrict__ x4, unsigned short* __restrict__ xb,
                 const float* __restrict__ w0, const float* __restrict__ w1,
                 const float* __restrict__ w2, const float* __restrict__ w3,
                 const float* __restrict__ w4, unsigned short* __restrict__ dst_all) {
  const int t = threadIdx.x;
  if (blockIdx.x < 4096) {
    int idx = blockIdx.x * 256 + t;
    float4 v = x4[idx];
    union { uint2 u; unsigned short s[4]; } o;
    o.s[0] = f2bf(v.x); o.s[1] = f2bf(v.y); o.s[2] = f2bf(v.z); o.s[3] = f2bf(v.w);
    *(uint2*)&xb[(size_t)idx * 4] = o.u;
    return;
  }
  const int b = blockIdx.x - 4096;
  const int z = b >> 8, ky = (b >> 4) & 15, nx = b & 15;
  const float* src = (z == 0) ? w0 : (z == 1) ? w1 : (z == 2) ? w2 : (z == 3) ? w3 : w4;
  unsigned short* dst = dst_all + (size_t)z * D_ * D_;
  __shared__ __align__(16) unsigned short tile[64 * 72];
  const int k0 = ky * 64, n0 = nx * 64;
#pragma unroll
  for (int c = 0; c < 4; ++c) {
    int idx = c * 256 + t;
    int r = idx >> 4, cc = (idx & 15) << 2;
    float4 v = *(const float4*)&src[(size_t)(k0 + r) * D_ + n0 + cc];
    tile[(cc + 0) * 72 + r] = f2bf(v.x);
    tile[(cc + 1) * 72 + r] = f2bf(v.y);
    tile[(cc + 2) * 72 + r] = f2bf(v.z);
    tile[(cc + 3) * 72 + r] = f2bf(v.w);
  }
  __syncthreads();
  int rr = t >> 2, ck = (t & 3) << 4;
  uint4 v0 = *(const uint4*)&tile[rr * 72 + ck];
  uint4 v1 = *(const uint4*)&tile[rr * 72 + ck + 8];
  *(uint4*)&dst[(size_t)(n0 + rr) * D_ + k0 + ck] = v0;
  *(uint4*)&dst[(size_t)(n0 + rr) * D_ + k0 + ck + 8] = v1;
}

// ------------------------------------------------------------------ QKV GEMM
// Q pre-scaled by 0.125*log2(e); Q,K bf16 -> [B,H,T,DH]; V fp16 k-shuffled
// V^T [d][kb][quad][j][r] staged via LDS for coalesced stores.
__global__ __launch_bounds__(256, 2)
void gemm_qkv(const unsigned short* __restrict__ A,
              const unsigned short* __restrict__ Bt,
              unsigned short* __restrict__ oQ, unsigned short* __restrict__ oK,
              _Float16* __restrict__ oV) {
  const int K = 1024;
  __shared__ __align__(16) unsigned short As[128 * 32];
  __shared__ __align__(16) unsigned short Bs[128 * 32];
  __shared__ __align__(16) _Float16 Cs[2 * 64 * 136];
  const int t = threadIdx.x;
  const int lane = t & 63, w = t >> 6;
  const int quad = lane >> 4, lm = lane & 15;
  const int wm = w >> 1, wn = w & 1;
  const int m0 = blockIdx.y * 128, n0 = blockIdx.x * 128;
  const int arow = w * 32 + (lane >> 2), acol = (lane & 3) << 3;

  floatx4 acc[4][4];
#pragma unroll
  for (int i = 0; i < 4; ++i)
#pragma unroll
    for (int j = 0; j < 4; ++j) acc[i][j] = (floatx4){0.f, 0.f, 0.f, 0.f};

  for (int kt = 0; kt < K; kt += 32) {
    const unsigned short* ga = A + (size_t)(m0 + arow) * K + kt + acol;
    const unsigned short* gb = Bt + (size_t)(n0 + arow) * K + kt + acol;
    GLD_LDS16(ga, &As[(w * 32) * 32]);
    GLD_LDS16(ga + (size_t)16 * K, &As[(w * 32 + 16) * 32]);
    GLD_LDS16(gb, &Bs[(w * 32) * 32]);
    GLD_LDS16(gb + (size_t)16 * K, &Bs[(w * 32 + 16) * 32]);
    __syncthreads();
    short8 a[4], b[4];
#pragma unroll
    for (int i = 0; i < 4; ++i) a[i] = *(const short8*)&As[(wm * 64 + i * 16 + lm) * 32 + quad * 8];
#pragma unroll
    for (int j = 0; j < 4; ++j) b[j] = *(const short8*)&Bs[(wn * 64 + j * 16 + lm) * 32 + quad * 8];
#pragma unroll
    for (int i = 0; i < 4; ++i)
#pragma unroll
      for (int j = 0; j < 4; ++j)
        acc[i][j] = __builtin_amdgcn_mfma_f32_16x16x32_bf16(a[i], b[j], acc[i][j], 0, 0, 0);
    __syncthreads();
  }

  if (n0 < 2048) {
    unsigned short* p = (n0 < 1024) ? oQ : oK;
    const float qscale = (n0 < 1024) ? 0.18033688f : 1.0f;   // 0.125*log2(e)
#pragma unroll
    for (int i = 0; i < 4; ++i) {
      int gmb = m0 + wm * 64 + i * 16 + quad * 4;
#pragma unroll
      for (int j = 0; j < 4; ++j) {
        int gn = n0 + wn * 64 + j * 16 + lm;
        int nn = gn & 1023, hh = nn >> 6, dd = nn & 63;
#pragma unroll
        for (int r = 0; r < 4; ++r) {
          int gm = gmb + r;
          int bb = gm >> 10, tt = gm & 1023;
          p[(((size_t)bb * H_ + hh) * T_ + tt) * DH_ + dd] = f2bf(acc[i][j][r] * qscale);
        }
      }
    }
  } else {
#pragma unroll
    for (int i = 0; i < 4; ++i) {
#pragma unroll
      for (int j = 0; j < 4; ++j) {
        int gn = n0 + wn * 64 + j * 16 + lm;
        int hd = (gn >> 6) & 1, dd = gn & 63;
        int kperm = quad * 32 + (wm * 4 + i) * 4;
        union { _Float16 h[4]; uint2 u; } pk;
#pragma unroll
        for (int r = 0; r < 4; ++r) pk.h[r] = (_Float16)acc[i][j][r];
        *(uint2*)&Cs[((size_t)(hd * 64 + dd)) * 136 + kperm] = pk.u;
      }
    }
    __syncthreads();
    const int row = t >> 1, half = t & 1;
    const int hd = row >> 6, dd = row & 63;
    const int hh = ((n0 & 1023) >> 6) + hd;
    const int bb = m0 >> 10, kbg = (m0 >> 7) & 7;
    const _Float16* srcp = &Cs[(size_t)(hd * 64 + dd) * 136 + half * 64];
    _Float16* dstp = oV + ((((size_t)bb * H_ + hh) * DH_ + dd) * 8 + kbg) * 128 + half * 64;
#pragma unroll
    for (int g = 0; g < 8; ++g)
      *(uint4*)(dstp + g * 8) = *(const uint4*)(srcp + g * 8);
  }
}

// ------------------------------------------------------------ FFN GEMM 64x128
template <int MODE>
__global__ __launch_bounds__(256, 2)
void gemm_ffn(const unsigned short* __restrict__ A,
              const unsigned short* __restrict__ Bt,
              unsigned short* __restrict__ oBf, float* __restrict__ oF,
              const float* __restrict__ bias) {
  const int K = 1024, N = 1024;
  __shared__ __align__(16) unsigned short As[64 * 32];
  __shared__ __align__(16) unsigned short Bs[128 * 32];
  const int t = threadIdx.x;
  const int lane = t & 63, w = t >> 6;
  const int quad = lane >> 4, lm = lane & 15;
  const int wm = w >> 1, wn = w & 1;
  const int m0 = blockIdx.y * 64, n0 = blockIdx.x * 128;
  const int lrow = lane >> 2, lcol = (lane & 3) << 3;

  floatx4 acc[2][4];
#pragma unroll
  for (int i = 0; i < 2; ++i)
#pragma unroll
    for (int j = 0; j < 4; ++j) acc[i][j] = (floatx4){0.f, 0.f, 0.f, 0.f};

  for (int kt = 0; kt < K; kt += 32) {
    const unsigned short* ga = A + (size_t)(m0 + w * 16 + lrow) * K + kt + lcol;
    const unsigned short* gb = Bt + (size_t)(n0 + w * 32 + lrow) * K + kt + lcol;
    GLD_LDS16(ga, &As[(w * 16) * 32]);
    GLD_LDS16(gb, &Bs[(w * 32) * 32]);
    GLD_LDS16(gb + (size_t)16 * K, &Bs[(w * 32 + 16) * 32]);
    __syncthreads();
    short8 a[2], b[4];
#pragma unroll
    for (int i = 0; i < 2; ++i) a[i] = *(const short8*)&As[(wm * 32 + i * 16 + lm) * 32 + quad * 8];
#pragma unroll
    for (int j = 0; j < 4; ++j) b[j] = *(const short8*)&Bs[(wn * 64 + j * 16 + lm) * 32 + quad * 8];
#pragma unroll
    for (int i = 0; i < 2; ++i)
#pragma unroll
      for (int j = 0; j < 4; ++j)
        acc[i][j] = __builtin_amdgcn_mfma_f32_16x16x32_bf16(a[i], b[j], acc[i][j], 0, 0, 0);
    __syncthreads();
  }

#pragma unroll
  for (int i = 0; i < 2; ++i) {
    int gmb = m0 + wm * 32 + i * 16 + quad * 4;
#pragma unroll
    for (int j = 0; j < 4; ++j) {
      int gn = n0 + wn * 64 + j * 16 + lm;
      float bv = bias[gn];
#pragma unroll
      for (int r = 0; r < 4; ++r) {
        int gm = gmb + r;
        float v = acc[i][j][r] + bv;
        if (MODE == 1) {
          oBf[(size_t)gm * N + gn] = f2bf(fmaxf(v, 0.f));
        } else {
          oF[(size_t)gm * N + gn] = v;
        }
      }
    }
  }
}

// --------------------------------------------------------------- flash attn
// 512 blocks x 256 thr; R8 body. bid decode: bid&7 = head%8 (all 8
// qb-blocks of a head on ONE XCD; FETCH 49->14MB measured in R11) AND
// bid/bid+256 complementary in qb (co-resident pair = 9 trips, balanced;
// R11 broke this -> 16-trip critical path, 67us). hgrp bits 3-5,
// qpair bits 6-7, qb = hi ? 7-qpair : qpair.
// Wave 3 of qb==7 blocks loops kb=0..7 with row 1023 never masked.
__global__ __launch_bounds__(256)
void flash_attn(const unsigned short* __restrict__ Qb,
                const unsigned short* __restrict__ Kb,
                const _Float16* __restrict__ Vtg,
                const float* __restrict__ maskp,
                unsigned short* __restrict__ attn) {
  const int t = threadIdx.x;
  const int lane = t & 63, w = t >> 6;
  const int quad = lane >> 4, lm = lane & 15;

  const int bid = blockIdx.x;               // 0..511
  const int hi  = bid >> 8;                 // 0/1: co-residency half
  const int lo  = bid & 255;
  const int xcd = lo & 7;
  const int hgrp = (lo >> 3) & 7;
  const int qpair = lo >> 6;                // 0..3
  const int qb = hi ? (7 - qpair) : qpair;  // pair (p, 7-p) share a CU
  const int head = hgrp * 8 + xcd;          // 0..63; head%8 = XCD
  const int hh = head & 15, bb = head >> 4;
  const int q0 = qb << 7;

  const size_t headoff = ((size_t)bb * H_ + hh) * T_ * DH_;
  const unsigned short* Qh = Qb + headoff;
  const unsigned short* Kh = Kb + headoff;
  const _Float16* Vh = Vtg + headoff;   // k-shuffled [d][kb][quad][j][r]

  short8 qf[2][2];
#pragma unroll
  for (int qg = 0; qg < 2; ++qg)
#pragma unroll
    for (int ks = 0; ks < 2; ++ks)
      qf[qg][ks] = *(const short8*)(Qh + (size_t)(q0 + w * 32 + qg * 16 + lm) * 64 + ks * 32 + quad * 8);

  float lsum[2] = {0.f, 0.f};
  floatx4 acc[2][4];
#pragma unroll
  for (int qg = 0; qg < 2; ++qg)
#pragma unroll
    for (int j2 = 0; j2 < 4; ++j2) acc[qg][j2] = (floatx4){0.f, 0.f, 0.f, 0.f};

  const int qglob0 = q0 + w * 32 + lm;
  const bool excl1 = (qglob0 + 16 == 1023);   // row-1023 lane (qg=1 only)
  const float MSHIFT = 14426.950408f;          // 10000*log2(e)

  const int kb_lo = (qb == 7 && w == 3) ? 0 : qb;

  // prologue: K fragments for kb_lo
  short8 kf[8][2];
  {
    const unsigned short* Kblk = Kh + (size_t)(kb_lo * 128) * 64;
#pragma unroll
    for (int j = 0; j < 8; ++j) {
      kf[j][0] = *(const short8*)(Kblk + (size_t)(j * 16 + lm) * 64 + quad * 8);
      kf[j][1] = *(const short8*)(Kblk + (size_t)(j * 16 + lm) * 64 + 32 + quad * 8);
    }
  }

  for (int kb = kb_lo; kb < 8; ++kb) {
    const int k0 = kb * 128;
    const bool need_mask = (kb <= qb);
    const bool has_next = (kb + 1 < 8);
    const unsigned short* Kn = Kh + (size_t)((kb + 1) * 128) * 64;

    // V loads for this kb (consumed in PV; hidden by S+softmax of j=0..)
    union { uint4 u[4]; _Float16 h[32]; } vf[4];
#pragma unroll
    for (int j2 = 0; j2 < 4; ++j2) {
      const _Float16* vp = Vh + ((size_t)(j2 * 16 + lm) * 8 + kb) * 128 + quad * 32;
#pragma unroll
      for (int g = 0; g < 4; ++g) vf[j2].u[g] = *(const uint4*)(vp + g * 8);
    }

#pragma unroll
    for (int j = 0; j < 8; ++j) {
      // S-MFMAs consume kf[j]
      floatx4 st[2];
#pragma unroll
      for (int qg = 0; qg < 2; ++qg) {
        floatx4 z = (floatx4){0.f, 0.f, 0.f, 0.f};
        z = __builtin_amdgcn_mfma_f32_16x16x32_bf16(kf[j][0], qf[qg][0], z, 0, 0, 0);
        st[qg] = __builtin_amdgcn_mfma_f32_16x16x32_bf16(kf[j][1], qf[qg][1], z, 0, 0, 0);
      }
      // rotate: prefetch kb+1's fragment j into kf[j] (lands ~7 j-steps later)
      if (has_next) {
        kf[j][0] = *(const short8*)(Kn + (size_t)(j * 16 + lm) * 64 + quad * 8);
        kf[j][1] = *(const short8*)(Kn + (size_t)(j * 16 + lm) * 64 + 32 + quad * 8);
      }
      // softmax j
      half4 pa[2];
#pragma unroll
      for (int qg = 0; qg < 2; ++qg) {
        const int qq = qglob0 + qg * 16;
        const bool skip = (qg == 1) && excl1;
#pragma unroll
        for (int r = 0; r < 4; ++r) {
          int kg = k0 + j * 16 + quad * 4 + r;
          float v = st[qg][r];
          if (need_mask && !skip && kg <= qq) v -= MSHIFT;
          float p = __builtin_amdgcn_exp2f(v);
          lsum[qg] += p;
          pa[qg][r] = (_Float16)p;
        }
      }
      // PV j
#pragma unroll
      for (int j2 = 0; j2 < 4; ++j2) {
        half4 vb;
#pragma unroll
        for (int r = 0; r < 4; ++r) vb[r] = vf[j2].h[j * 4 + r];
        acc[0][j2] = __builtin_amdgcn_mfma_f32_16x16x16f16(pa[0], vb, acc[0][j2], 0, 0, 0);
        acc[1][j2] = __builtin_amdgcn_mfma_f32_16x16x16f16(pa[1], vb, acc[1][j2], 0, 0, 0);
      }
    }
  }

  // epilogue
#pragma unroll
  for (int qg = 0; qg < 2; ++qg) {
    float l = lsum[qg];
    l += __shfl_xor(l, 16);
    l += __shfl_xor(l, 32);
    float s = maskp[bb * T_ + qglob0 + qg * 16] / l;
#pragma unroll
    for (int r = 0; r < 4; ++r) {
      float bsc = __shfl(s, quad * 4 + r);
      int tq = q0 + w * 32 + qg * 16 + quad * 4 + r;
#pragma unroll
      for (int j2 = 0; j2 < 4; ++j2)
        attn[((size_t)(bb * T_ + tq)) * D_ + hh * 64 + j2 * 16 + lm] = f2bf(acc[qg][j2][r] * bsc);
    }
  }
}

// --------------------------------------------- LN(x + attn_bf16) -> h1 f32+bf16
__global__ __launch_bounds__(256)
void ln_res_kernel(const float* __restrict__ xa, const unsigned short* __restrict__ attn,
                   const float* __restrict__ sc, const float* __restrict__ bi,
                   float* __restrict__ h, unsigned short* __restrict__ hb) {
  const int row = blockIdx.x, t = threadIdx.x;
  const int lane = t & 63, wid = t >> 6;
  size_t base = (size_t)row * D_ + t * 4;
  float4 a = *(const float4*)&xa[base];
  union { uint2 u; unsigned short s[4]; } au;
  au.u = *(const uint2*)&attn[base];
  float v0 = a.x + bf2f(au.s[0]), v1 = a.y + bf2f(au.s[1]);
  float v2 = a.z + bf2f(au.s[2]), v3 = a.w + bf2f(au.s[3]);
  float s1 = v0 + v1 + v2 + v3;
  float s2 = v0 * v0 + v1 * v1 + v2 * v2 + v3 * v3;
#pragma unroll
  for (int off = 32; off; off >>= 1) { s1 += __shfl_down(s1, off); s2 += __shfl_down(s2, off); }
  __shared__ float r1[4], r2[4];
  if (lane == 0) { r1[wid] = s1; r2[wid] = s2; }
  __syncthreads();
  s1 = r1[0] + r1[1] + r1[2] + r1[3];
  s2 = r2[0] + r2[1] + r2[2] + r2[3];
  float mean = s1 * (1.f / 1024.f);
  float var = s2 * (1.f / 1024.f) - mean * mean;
  float rstd = rsqrtf(var + 1e-5f);
  float4 sv = *(const float4*)&sc[t * 4];
  float4 bv = *(const float4*)&bi[t * 4];
  float o0 = (v0 - mean) * rstd * sv.x + bv.x;
  float o1 = (v1 - mean) * rstd * sv.y + bv.y;
  float o2 = (v2 - mean) * rstd * sv.z + bv.z;
  float o3 = (v3 - mean) * rstd * sv.w + bv.w;
  float4 ov = {o0, o1, o2, o3};
  *(float4*)&h[base] = ov;
  union { uint2 u; unsigned short s[4]; } ob;
  ob.s[0] = f2bf(o0); ob.s[1] = f2bf(o1); ob.s[2] = f2bf(o2); ob.s[3] = f2bf(o3);
  *(uint2*)&hb[base] = ob.u;
}

// --------------------------------------- out = LN(LN(h1+ffn,ln2),ln3)
__global__ __launch_bounds__(256)
void ln_double_kernel(const float* __restrict__ h1, const float* __restrict__ ffn,
                      const float* __restrict__ s2c, const float* __restrict__ b2c,
                      const float* __restrict__ s3c, const float* __restrict__ b3c,
                      float* __restrict__ out) {
  const int row = blockIdx.x, t = threadIdx.x;
  const int lane = t & 63, wid = t >> 6;
  size_t base = (size_t)row * D_ + t * 4;
  float4 a = *(const float4*)&h1[base];
  float4 b = *(const float4*)&ffn[base];
  float v0 = a.x + b.x, v1 = a.y + b.y, v2 = a.z + b.z, v3 = a.w + b.w;
  float s1 = v0 + v1 + v2 + v3;
  float s2 = v0 * v0 + v1 * v1 + v2 * v2 + v3 * v3;
#pragma unroll
  for (int off = 32; off; off >>= 1) { s1 += __shfl_down(s1, off); s2 += __shfl_down(s2, off); }
  __shared__ float ra[4], rb[4], rc[4], rd[4];
  if (lane == 0) { ra[wid] = s1; rb[wid] = s2; }
  __syncthreads();
  s1 = ra[0] + ra[1] + ra[2] + ra[3];
  s2 = rb[0] + rb[1] + rb[2] + rb[3];
  float mean = s1 * (1.f / 1024.f);
  float var = s2 * (1.f / 1024.f) - mean * mean;
  float rstd = rsqrtf(var + 1e-5f);
  float4 sv = *(const float4*)&s2c[t * 4];
  float4 bv = *(const float4*)&b2c[t * 4];
  float o0 = (v0 - mean) * rstd * sv.x + bv.x;
  float o1 = (v1 - mean) * rstd * sv.y + bv.y;
  float o2 = (v2 - mean) * rstd * sv.z + bv.z;
  float o3 = (v3 - mean) * rstd * sv.w + bv.w;
  float u1 = o0 + o1 + o2 + o3;
  float u2 = o0 * o0 + o1 * o1 + o2 * o2 + o3 * o3;
#pragma unroll
  for (int off = 32; off; off >>= 1) { u1 += __shfl_down(u1, off); u2 += __shfl_down(u2, off); }
  if (lane == 0) { rc[wid] = u1; rd[wid] = u2; }
  __syncthreads();
  u1 = rc[0] + rc[1] + rc[2] + rc[3];
  u2 = rd[0] + rd[1] + rd[2] + rd[3];
  float mean2 = u1 * (1.f / 1024.f);
  float var2 = u2 * (1.f / 1024.f) - mean2 * mean2;
  float rstd2 = rsqrtf(var2 + 1e-5f);
  float4 s3v = *(const float4*)&s3c[t * 4];
  float4 b3v = *(const float4*)&b3c[t * 4];
  float4 fo;
  fo.x = (o0 - mean2) * rstd2 * s3v.x + b3v.x;
  fo.y = (o1 - mean2) * rstd2 * s3v.y + b3v.y;
  fo.z = (o2 - mean2) * rstd2 * s3v.z + b3v.z;
  fo.w = (o3 - mean2) * rstd2 * s3v.w + b3v.w;
  *(float4*)&out[base] = fo;
}

// ------------------------------------------------------------------ launch
extern "C" void kernel_launch(void* const* d_in, const int* in_sizes, int n_in,
                              void* d_out, int out_size, void* d_ws, size_t ws_size,
                              hipStream_t stream) {
  (void)in_sizes; (void)n_in; (void)out_size; (void)ws_size;
  const float* x   = (const float*)d_in[0];
  const float* msk = (const float*)d_in[1];
  const float* wq  = (const float*)d_in[2];
  const float* wk  = (const float*)d_in[3];
  const float* wv  = (const float*)d_in[4];
  const float* w1  = (const float*)d_in[5];
  const float* b1  = (const float*)d_in[6];
  const float* w2  = (const float*)d_in[7];
  const float* b2  = (const float*)d_in[8];
  const float* l1s = (const float*)d_in[9];
  const float* l1b = (const float*)d_in[10];
  const float* l2s = (const float*)d_in[11];
  const float* l2b = (const float*)d_in[12];
  const float* l3s = (const float*)d_in[13];
  const float* l3b = (const float*)d_in[14];
  float* outp = (float*)d_out;

  char* ws = (char*)d_ws;
  unsigned short* xb   = (unsigned short*)(ws);                       // 8 MB
  unsigned short* wt   = (unsigned short*)(ws + ((size_t)8  << 20));  // 10 MB
  unsigned short* Qb   = (unsigned short*)(ws + ((size_t)18 << 20));  // 8 MB [B,H,T,DH]
  unsigned short* Kb   = (unsigned short*)(ws + ((size_t)26 << 20));  // 8 MB
  _Float16*       Vtg  = (_Float16*)(ws + ((size_t)34 << 20));        // 8 MB k-shuffled V^T
  unsigned short* attn = (unsigned short*)(ws + ((size_t)42 << 20));  // 8 MB bf16 [B,T,D]
  float* h1            = (float*)(ws + ((size_t)50 << 20));           // 16 MB
  unsigned short* h1b  = (unsigned short*)(ws + ((size_t)18 << 20));  // reuse Qb
  unsigned short* gb   = (unsigned short*)(ws + ((size_t)26 << 20));  // reuse Kb
  float* ffn           = (float*)(ws + ((size_t)34 << 20));           // reuse Vtg+attn

  prep_kernel<<<4096 + 1280, 256, 0, stream>>>((const float4*)x, xb,
                                               wq, wk, wv, w1, w2, wt);
  gemm_qkv<<<dim3(24, 32), 256, 0, stream>>>(xb, wt, Qb, Kb, Vtg);
  flash_attn<<<512, 256, 0, stream>>>(Qb, Kb, Vtg, msk, attn);
  ln_res_kernel<<<4096, 256, 0, stream>>>(x, attn, l1s, l1b, h1, h1b);
  gemm_ffn<1><<<dim3(8, 64), 256, 0, stream>>>(h1b, wt + (size_t)3 * 1024 * 1024, gb, nullptr, b1);
  gemm_ffn<2><<<dim3(8, 64), 256, 0, stream>>>(gb, wt + (size_t)4 * 1024 * 1024, nullptr, ffn, b2);
  ln_double_kernel<<<4096, 256, 0, stream>>>(h1, ffn, l2s, l2b, l3s, l3b, outp);
}